// Round 20
// baseline (2129.395 us; speedup 1.0000x reference)
//
#include <hip/hip_runtime.h>
#include <math.h>

#define NS 72
#define NS2 (NS*NS)          // 5184
#define NS3 (NS*NS*NS)       // 373248
#define MZ 8
#define LALPHA 0.05f
#define CSCALE (1.0f/256.0f)

typedef _Float16 f16x8 __attribute__((ext_vector_type(8)));
typedef _Float16 f16x4 __attribute__((ext_vector_type(4)));
typedef float f32x4 __attribute__((ext_vector_type(4)));

__device__ __forceinline__ float leakyf(float v){ return v > 0.f ? v : LALPHA*v; }

// octant regions: x0, nx, y0, ny  (kz always [0,8))
__constant__ int c_RX0[8] = {0,64,0,64, 8,0,8,64};
__constant__ int c_RNX[8] = {8,8,8,8, 56,8,56,8};
__constant__ int c_RY0[8] = {0,0,64,64, 0,8,64,8};
__constant__ int c_RNY[8] = {8,8,8,8, 8,56,8,56};
// fp16 B boxes: base (in elements), BY = ny+4
__constant__ int c_Bbase[8] = {0,1728,3456,5184, 6912,15552,24192,32832};
__constant__ int c_BY[8]    = {12,12,12,12, 12,60,12,60};

__global__ void k_tw(float2* tw){
  int t = threadIdx.x;
  if (t < NS){
    double th = (2.0*M_PI/72.0)*(double)t;
    tw[t] = make_float2((float)cos(th), (float)sin(th));
  }
}

// transpose fc1 weights to [j][c] once
__global__ void k_wpackT(const float* __restrict__ w1, float* __restrict__ w1t){
  int e = blockIdx.x*256 + threadIdx.x;            // 4096
  int j = e >> 5, c = e & 31;
  w1t[e] = w1[c*128 + j];
}

__global__ void k_fc0(const float* __restrict__ yx, const float* __restrict__ yy,
                      const float* __restrict__ yz, const float* __restrict__ w,
                      const float* __restrict__ b, float* __restrict__ X){
  int idx = blockIdx.x*256 + threadIdx.x;
  int z = idx % NS; int t = idx / NS; int y = t % NS; t /= NS; int x = t % NS; int c = t / NS;
  float v = 0.f;
  if (x < 64 && y < 64 && z < 64){
    int p = (x*64 + y)*64 + z;
    float i0 = yx[p], i1 = yy[p], i2 = yz[p];
    float gx = (float)x*(1.f/63.f), gy = (float)y*(1.f/63.f), gz = (float)z*(1.f/63.f);
    v = b[c] + i0*w[0*32+c] + i1*w[1*32+c] + i2*w[2*32+c]
             + gx*w[3*32+c] + gy*w[4*32+c] + gz*w[5*32+c];
  }
  X[idx] = v;
}

// ---------------- truncated DFT chain ----------------
__global__ void k_zdft(const float* __restrict__ X, float2* __restrict__ A, const float2* __restrict__ tw){
  __shared__ float2 stw[NS];
  int tid = threadIdx.x;
  if (tid < NS) stw[tid] = tw[tid];
  __syncthreads();
  int f = blockIdx.x*256 + tid;
  const float* row = X + (size_t)f*NS;
  float ar[MZ], ai[MZ]; int tk[MZ];
  #pragma unroll
  for (int k=0;k<MZ;k++){ ar[k]=0.f; ai[k]=0.f; tk[k]=0; }
  for (int z4=0; z4<NS; z4+=4){
    float4 v4 = *(const float4*)(row + z4);
    float vs[4] = {v4.x, v4.y, v4.z, v4.w};
    #pragma unroll
    for (int zz=0; zz<4; zz++){
      float v = vs[zz];
      #pragma unroll
      for (int k=0;k<MZ;k++){
        float2 w = stw[tk[k]];
        ar[k] += v*w.x;
        ai[k] -= v*w.y;
        tk[k] += k; if (tk[k] >= NS) tk[k] -= NS;
      }
    }
  }
  float2* o = A + (size_t)f*MZ;
  #pragma unroll
  for (int k=0;k<MZ;k++) o[k] = make_float2(ar[k], ai[k]);
}

__global__ void k_ydft(const float2* __restrict__ A, float2* __restrict__ B, const float2* __restrict__ tw){
  __shared__ float2 stw[NS];
  int tid = threadIdx.x;
  if (tid < NS) stw[tid] = tw[tid];
  __syncthreads();
  int f = blockIdx.x*256 + tid;
  int ky = f % NS; int cx = f / NS;
  const float2* in = A + (size_t)cx*NS*MZ;
  float ar[MZ], ai[MZ];
  #pragma unroll
  for (int k=0;k<MZ;k++){ ar[k]=0.f; ai[k]=0.f; }
  int t = 0;
  for (int y=0;y<NS;y++){
    float2 w = stw[t]; t += ky; if (t>=NS) t-=NS;
    const float2* iy = in + y*MZ;
    #pragma unroll
    for (int k=0;k<MZ;k++){
      float2 v = iy[k];
      ar[k] += v.x*w.x + v.y*w.y;
      ai[k] += v.y*w.x - v.x*w.y;
    }
  }
  float2* o = B + (size_t)f*MZ;
  #pragma unroll
  for (int k=0;k<MZ;k++) o[k] = make_float2(ar[k], ai[k]);
}

// x-DFT restricted to the L-frame (2048 (kx,ky) pairs), 4 modes per thread
__global__ void k_xdftL(const float2* __restrict__ B, float2* __restrict__ C, const float2* __restrict__ tw){
  __shared__ float2 stw[NS];
  int tid = threadIdx.x;
  if (tid < NS) stw[tid] = tw[tid];
  __syncthreads();
  int t = blockIdx.x*256 + tid;                    // 131072 = 32c * 2048l * 2h
  int h = t & 1; int t2 = t >> 1;
  int c = t2 >> 11; int l = t2 & 2047;
  int kx, ky;
  if (l < 576){ ky = l & 7; kx = l >> 3; }
  else if (l < 1152){ int e = l - 576; ky = 64 + (e & 7); kx = e >> 3; }
  else { int e = l - 1152; int kyi = e >> 4; int kxi = e & 15;
         ky = 8 + kyi; kx = (kxi < 8) ? kxi : 56 + kxi; }
  int k0 = h*4;
  const float2* in = B + ((size_t)c*NS2 + ky)*MZ + k0;
  float ar[4], ai[4];
  #pragma unroll
  for (int k=0;k<4;k++){ ar[k]=0.f; ai[k]=0.f; }
  int tt = 0;
  for (int x=0;x<NS;x++){
    float2 w = stw[tt]; tt += kx; if (tt>=NS) tt-=NS;
    const float2* ix = in + (size_t)x*NS*MZ;
    #pragma unroll
    for (int k=0;k<4;k++){
      float2 v = ix[k];
      ar[k] += v.x*w.x + v.y*w.y;
      ai[k] += v.y*w.x - v.x*w.y;
    }
  }
  float2* o = C + (((size_t)c*NS + kx)*NS + ky)*MZ + k0;
  #pragma unroll
  for (int k=0;k<4;k++) o[k] = make_float2(ar[k], ai[k]);
}

// spectral weights fp32 -> fp16 A[r][tap][o=64][i=64], A[o][i] = w[o][(i&1)*32 + (i>>1)]
__global__ void k_wpackh(const float* __restrict__ W, _Float16* __restrict__ Ah){
  int e = blockIdx.x*256 + threadIdx.x;            // 4,096,000
  int i = e & 63; int o = (e>>6) & 63;
  int t2 = e >> 12; int tap = t2 % 125; int r = t2 / 125;
  const float* wr = W + (size_t)r*64*64*125;
  Ah[e] = (_Float16)wr[((size_t)(o*64 + (i&1)*32 + (i>>1)))*125 + tap];
}

// C -> fp16 region boxes Bg[elem][64], halo zeros, scaled
__global__ void k_cpackh(const float2* __restrict__ C, _Float16* __restrict__ Bg){
  int g = blockIdx.x*256 + threadIdx.x;            // 1,327,104
  int ci = g & 31; int elem = g >> 5;
  int r = 0;
  #pragma unroll
  for (int k=1;k<8;k++) if (elem >= c_Bbase[k]) r = k;
  int el = elem - c_Bbase[r];
  int BY = c_BY[r];
  int q3 = el % 12; int tt = el / 12; int q2 = tt % BY; int q1 = tt / BY;
  int kxr = q1-2, kyr = q2-2, kzr = q3-2;
  float2 v = make_float2(0.f,0.f);
  if ((unsigned)kxr < (unsigned)c_RNX[r] && (unsigned)kyr < (unsigned)c_RNY[r] && (unsigned)kzr < 8u){
    v = C[(((size_t)ci*NS + (c_RX0[r]+kxr))*NS + (c_RY0[r]+kyr))*MZ + kzr];
  }
  _Float16* o = Bg + (size_t)elem*64 + 2*ci;
  o[0] = (_Float16)(v.x*CSCALE);
  o[1] = (_Float16)(v.y*CSCALE);
}

// freq conv MFMA with fused in-LDS K-split reduction.
__global__ __launch_bounds__(512) void k_freqmfma2(const _Float16* __restrict__ Ah,
                                                   const _Float16* __restrict__ Bg,
                                                   float* __restrict__ Df){
  __shared__ float sAcc[2][64*65];                 // 33.3 KB
  int tid = threadIdx.x;
  int orig = blockIdx.x;                           // [0,256)
  int b = (orig & 7)*32 + (orig >> 3);             // XCD chunk swizzle (8x32 exact)
  int r, til;
  if (b < 32){ r = b>>3; til = b&7; }
  else       { r = 4 + (b-32)/56; til = (b-32)%56; }
  int x0 = c_RX0[r], y0 = c_RY0[r], BY = c_BY[r];
  int q1, q2base;
  if (r==5 || r==7){ q1 = 2 + til/7; q2base = 2 + (til%7)*8; }
  else             { q1 = 2 + til;   q2base = 2; }
  int wv = tid >> 6;
  int lane = tid & 63;
  int l15 = lane & 15, kg = lane >> 4;
  int q2l = q2base + (l15>>3), q3l = 2 + (l15&7);
  const _Float16* Ar = Ah + (size_t)r*125*4096;
  const _Float16* Br = Bg + (size_t)c_Bbase[r]*64;
  int lb = q2l*12 + q3l;
  f32x4 acc[4][4];
  f32x4 zz = {0.f,0.f,0.f,0.f};
  #pragma unroll
  for (int m=0;m<4;m++)
    #pragma unroll
    for (int n=0;n<4;n++) acc[m][n] = zz;
  int t0 = wv*16;
  int t1 = t0+16 < 125 ? t0+16 : 125;
  for (int tt=t0; tt<t1; tt++){
    int td = tt/25; int rm = tt - td*25; int th = rm/5; int tz = rm - th*5;
    const _Float16* At = Ar + tt*4096;
    f16x8 a[4][2];
    #pragma unroll
    for (int mt=0;mt<4;mt++){
      a[mt][0] = *(const f16x8*)(At + (mt*16+l15)*64 + kg*8);
      a[mt][1] = *(const f16x8*)(At + (mt*16+l15)*64 + 32 + kg*8);
    }
    int ebase = (q1 + td - 2)*BY*12 + lb + (th-2)*12 + (tz-2);
    f16x8 bf[4][2];
    #pragma unroll
    for (int nt=0;nt<4;nt++){
      const _Float16* bp = Br + (size_t)(ebase + nt*24)*64 + kg*8;
      bf[nt][0] = *(const f16x8*)(bp);
      bf[nt][1] = *(const f16x8*)(bp + 32);
    }
    #pragma unroll
    for (int mt=0;mt<4;mt++)
      #pragma unroll
      for (int nt=0;nt<4;nt++){
        acc[mt][nt] = __builtin_amdgcn_mfma_f32_16x16x32_f16(a[mt][0], bf[nt][0], acc[mt][nt],0,0,0);
        acc[mt][nt] = __builtin_amdgcn_mfma_f32_16x16x32_f16(a[mt][1], bf[nt][1], acc[mt][nt],0,0,0);
      }
  }
  int hb = wv >> 2, ph = wv & 3;
  float* dst = sAcc[hb] + lane*65;
  for (int p=0; p<4; p++){
    if (ph == p){
      #pragma unroll
      for (int mt=0;mt<4;mt++)
        #pragma unroll
        for (int nt=0;nt<4;nt++){
          int e = mt*16 + nt*4;
          if (p == 0){
            dst[e+0] = acc[mt][nt][0]; dst[e+1] = acc[mt][nt][1];
            dst[e+2] = acc[mt][nt][2]; dst[e+3] = acc[mt][nt][3];
          } else {
            dst[e+0] += acc[mt][nt][0]; dst[e+1] += acc[mt][nt][1];
            dst[e+2] += acc[mt][nt][2]; dst[e+3] += acc[mt][nt][3];
          }
        }
    }
    __syncthreads();
  }
  int lane2 = tid & 63;
  int pr = tid >> 6;
  int mt = pr >> 1, ntb = (pr & 1)*2;
  int l15b = lane2 & 15, kgb = lane2 >> 4;
  int q2b = q2base + (l15b>>3), q3b = 2 + (l15b&7);
  int kx = x0 + q1 - 2;
  int kz = q3b - 2;
  const float* s0 = sAcc[0] + lane2*65;
  const float* s1 = sAcc[1] + lane2*65;
  #pragma unroll
  for (int dn=0; dn<2; dn++){
    int nt = ntb + dn;
    int ky = y0 + q2b + nt*2 - 2;
    #pragma unroll
    for (int rg=0; rg<4; rg++){
      int e = mt*16 + nt*4 + rg;
      int o = mt*16 + kgb*4 + rg;
      int co = o >> 1, reim = o & 1;
      Df[((((size_t)co*NS + kx)*NS + ky)*MZ + kz)*2 + reim] = (s0[e] + s1[e])*256.0f;
    }
  }
}

// inverse x-DFT with L-frame trimming. Thread map f = (ky slowest, c, x fastest)
__global__ void k_invx(const float2* __restrict__ D, float2* __restrict__ E, const float2* __restrict__ tw){
  __shared__ float2 stw[NS];
  int tid = threadIdx.x;
  if (tid < NS) stw[tid] = tw[tid];
  __syncthreads();
  int f = blockIdx.x*256 + tid;
  int ky = f / 2304; int rem = f - ky*2304;
  int c = rem / NS; int x = rem - c*NS;
  const float2* in = D + ((size_t)c*NS2 + ky)*MZ;
  float ar[MZ], ai[MZ];
  #pragma unroll
  for (int k=0;k<MZ;k++){ ar[k]=0.f; ai[k]=0.f; }
  if (ky >= 8 && ky < 64){
    int t = 0;
    for (int kx=0;kx<8;kx++){
      float2 w = stw[t]; t += x; if (t>=NS) t-=NS;
      const float2* ix = in + (size_t)kx*NS*MZ;
      #pragma unroll
      for (int k=0;k<MZ;k++){
        float2 v = ix[k];
        ar[k] += v.x*w.x - v.y*w.y;
        ai[k] += v.x*w.y + v.y*w.x;
      }
    }
    t = (64*x) % NS;
    for (int kx=64;kx<NS;kx++){
      float2 w = stw[t]; t += x; if (t>=NS) t-=NS;
      const float2* ix = in + (size_t)kx*NS*MZ;
      #pragma unroll
      for (int k=0;k<MZ;k++){
        float2 v = ix[k];
        ar[k] += v.x*w.x - v.y*w.y;
        ai[k] += v.x*w.y + v.y*w.x;
      }
    }
  } else {
    int t = 0;
    for (int kx=0;kx<NS;kx++){
      float2 w = stw[t]; t += x; if (t>=NS) t-=NS;
      const float2* ix = in + (size_t)kx*NS*MZ;
      #pragma unroll
      for (int k=0;k<MZ;k++){
        float2 v = ix[k];
        ar[k] += v.x*w.x - v.y*w.y;
        ai[k] += v.x*w.y + v.y*w.x;
      }
    }
  }
  float2* o = E + (((size_t)c*NS + x)*NS + ky)*MZ;
  #pragma unroll
  for (int k=0;k<MZ;k++) o[k] = make_float2(ar[k]*(1.f/72.f), ai[k]*(1.f/72.f));
}

// fused invy+invz, writing fp16 X1h (channel-major [c][x][y][z]), f16x4 stores
__global__ void k_invyz(const float2* __restrict__ E, _Float16* __restrict__ X1h, const float2* __restrict__ tw){
  __shared__ float2 stw[NS];
  int tid = threadIdx.x;
  if (tid < NS) stw[tid] = tw[tid];
  __syncthreads();
  int f = blockIdx.x*256 + tid;
  int y = f % NS; int t2 = f / NS; int x = t2 % NS; int c = t2 / NS;
  const float2* in = E + ((size_t)c*NS + x)*NS*MZ;
  float ar[MZ], ai[MZ];
  #pragma unroll
  for (int k=0;k<MZ;k++){ ar[k]=0.f; ai[k]=0.f; }
  int t = 0;
  for (int ky=0;ky<NS;ky++){
    float2 w = stw[t]; t += y; if (t>=NS) t-=NS;
    const float2* ik = in + ky*MZ;
    #pragma unroll
    for (int k=0;k<MZ;k++){
      float2 v = ik[k];
      ar[k] += v.x*w.x - v.y*w.y;
      ai[k] += v.x*w.y + v.y*w.x;
    }
  }
  const float scale = 1.f/(72.f*72.f);
  _Float16* o = X1h + (size_t)f*NS;
  int tk[MZ];
  #pragma unroll
  for (int k=0;k<MZ;k++) tk[k]=0;
  for (int z4=0; z4<NS; z4+=4){
    f16x4 hv;
    #pragma unroll
    for (int zz=0; zz<4; zz++){
      float acc = ar[0];
      #pragma unroll
      for (int k=1;k<MZ;k++){
        float2 w = stw[tk[k]];
        acc += 2.f*(ar[k]*w.x - ai[k]*w.y);
        tk[k] += k; if (tk[k] >= NS) tk[k] -= NS;
      }
      hv[zz] = (_Float16)(acc*scale);
    }
    *(f16x4*)(o + z4) = hv;
  }
}

// ---------------- fp16 MFMA conv path ----------------

// both conv weights fp32 [co][ci][27] -> fp16 [tap][co][ci]
__global__ void k_wcvt2(const float* __restrict__ w1, const float* __restrict__ w2,
                        _Float16* __restrict__ WhA, _Float16* __restrict__ WhB){
  int e = blockIdx.x*256 + threadIdx.x;            // 55296
  int h = e >= 27648; int e2 = e - (h ? 27648 : 0);
  int tap = e2 >> 10; int co = (e2>>5)&31; int ci = e2&31;
  const float* w = h ? w2 : w1;
  _Float16* o = h ? WhB : WhA;
  o[e2] = (_Float16)w[(co*32+ci)*27 + tap];
}

// fp32 [c][p] -> fp16 channel-last [p][c]; blocks 1458,1459 zero the +/-4096 guards
__global__ void k_cvt16(const float* __restrict__ Xf, _Float16* __restrict__ Xg){
  int b = blockIdx.x;
  int tid = threadIdx.x;
  if (b >= 1458){
    _Float16* g = (b==1458) ? (Xg - 4096) : (Xg + (size_t)NS3*32);
    f16x8 zz = {0,0,0,0,0,0,0,0};
    f16x8* gp = (f16x8*)g;
    gp[tid] = zz; gp[tid+256] = zz;
    return;
  }
  int p = b*256 + tid;
  f16x8 o0,o1,o2,o3;
  #pragma unroll
  for (int c=0;c<8;c++){
    o0[c] = (_Float16)Xf[(size_t)c*NS3 + p];
    o1[c] = (_Float16)Xf[(size_t)(c+8)*NS3 + p];
    o2[c] = (_Float16)Xf[(size_t)(c+16)*NS3 + p];
    o3[c] = (_Float16)Xf[(size_t)(c+24)*NS3 + p];
  }
  f16x8* op = (f16x8*)(Xg + (size_t)p*32);
  op[0]=o0; op[1]=o1; op[2]=o2; op[3]=o3;
}

// zero the +/-4096-half guards of an fp16 buffer (data ptr)
__global__ void k_zgH(_Float16* __restrict__ Hg){
  int e = blockIdx.x*256 + threadIdx.x;            // 1024
  _Float16* g = (e < 512) ? (Hg - 4096 + e*8)
                          : (Hg + (size_t)NS3*32 + (size_t)(e-512)*8);
  f16x8 zz = {0,0,0,0,0,0,0,0};
  *(f16x8*)g = zz;
}

// implicit-GEMM conv via mfma_f32_16x16x32_f16 with LDS-staged B operand and
// XOR chunk-swizzle. 648 blocks x 576 threads (9 waves, one 576-pos tile;
// 9 tiles/slab). Per dx: stage 722-row window [q0-73, q0+648] (46.2 KB).
// XCD swizzle: 648 = 8*81 exact.
// mode2=0: fp16 [p][c] OUTH. mode2=1: fp32 OUT with fp16 residuals.
__global__ __launch_bounds__(576) void k_convm(const _Float16* __restrict__ Xg,
    const _Float16* __restrict__ Wh, float* __restrict__ OUT, _Float16* __restrict__ OUTH,
    const _Float16* __restrict__ X1h, const _Float16* __restrict__ XresH,
    int mode2, int do_leaky){
  __shared__ _Float16 sB[722*32];                  // 46208 B
  int tid = threadIdx.x;
  int orig = blockIdx.x;                           // [0,648)
  int xcd = orig & 7, loc = orig >> 3;
  int wg = xcd*81 + loc;
  int slab = wg/9, tb = wg - slab*9;
  int q0 = tb*576;
  int wid = tid >> 6;
  int lane = tid & 63;
  int l15 = lane & 15, kg = lane >> 4;
  f32x4 acc[2][4];
  f32x4 zz = {0.f,0.f,0.f,0.f};
  #pragma unroll
  for (int a=0;a<2;a++)
    #pragma unroll
    for (int b=0;b<4;b++) acc[a][b] = zz;
  int wbase = l15*32 + kg*8;
  int lbase = wid*64 + 73 + l15;                   // LDS row base for this lane
  for (int dx=0; dx<3; dx++){
    int xx = slab + dx - 1;
    if ((unsigned)xx >= 72u) continue;             // slab is block-uniform
    __syncthreads();                               // protect previous window reads
    {
      const f16x8* src = (const f16x8*)(Xg + ((long long)xx*5184 + q0 - 73)*32);
      f16x8* dst = (f16x8*)sB;
      for (int e=tid; e<2888; e+=576){
        int es = (e & ~3) | ((e & 3) ^ ((e >> 3) & 3));
        dst[es] = src[e];
      }
    }
    __syncthreads();
    const _Float16* Wdx = Wh + dx*9216;
    #pragma unroll
    for (int t9=0; t9<9; t9++){
      int off = ((t9/3)-1)*72 + (t9%3) - 1;
      const _Float16* wp = Wdx + t9*1024 + wbase;
      f16x8 a0 = *(const f16x8*)(wp);
      f16x8 a1 = *(const f16x8*)(wp + 512);
      int rr = lbase + off;
      const _Float16* bb = sB + (((rr << 2) | (kg ^ ((rr >> 1) & 3)))*8);
      f16x8 b0 = *(const f16x8*)(bb);
      f16x8 b1 = *(const f16x8*)(bb + 512);
      f16x8 b2 = *(const f16x8*)(bb + 1024);
      f16x8 b3 = *(const f16x8*)(bb + 1536);
      acc[0][0] = __builtin_amdgcn_mfma_f32_16x16x32_f16(a0,b0,acc[0][0],0,0,0);
      acc[0][1] = __builtin_amdgcn_mfma_f32_16x16x32_f16(a0,b1,acc[0][1],0,0,0);
      acc[0][2] = __builtin_amdgcn_mfma_f32_16x16x32_f16(a0,b2,acc[0][2],0,0,0);
      acc[0][3] = __builtin_amdgcn_mfma_f32_16x16x32_f16(a0,b3,acc[0][3],0,0,0);
      acc[1][0] = __builtin_amdgcn_mfma_f32_16x16x32_f16(a1,b0,acc[1][0],0,0,0);
      acc[1][1] = __builtin_amdgcn_mfma_f32_16x16x32_f16(a1,b1,acc[1][1],0,0,0);
      acc[1][2] = __builtin_amdgcn_mfma_f32_16x16x32_f16(a1,b2,acc[1][2],0,0,0);
      acc[1][3] = __builtin_amdgcn_mfma_f32_16x16x32_f16(a1,b3,acc[1][3],0,0,0);
    }
  }
  int q0w = q0 + wid*64;
  if (mode2){
    #pragma unroll
    for (int nt=0; nt<4; nt++){
      int q = q0w + nt*16 + l15;
      int y = q/72, z = q - y*72;
      bool edge = (y==0)||(y==71)||(z==0)||(z==71);
      #pragma unroll
      for (int c2=0;c2<2;c2++){
        #pragma unroll
        for (int r=0;r<4;r++){
          int co = c2*16 + kg*4 + r;
          size_t idx = (size_t)co*NS3 + (size_t)slab*5184 + q;
          float v = acc[c2][nt][r];
          if (!edge){
            v += (float)X1h[idx] + (float)XresH[((size_t)slab*5184 + q)*32 + co];
            if (do_leaky) v = leakyf(v);
          }
          OUT[idx] = v;
        }
      }
    }
  } else {
    #pragma unroll
    for (int nt=0; nt<4; nt++){
      int q = q0w + nt*16 + l15;
      int y = q/72, z = q - y*72;
      bool edge = (y==0)||(y==71)||(z==0)||(z==71);
      _Float16* hp = OUTH + ((size_t)slab*5184 + q)*32 + kg*4;
      #pragma unroll
      for (int c2=0;c2<2;c2++){
        f32x4 av = acc[c2][nt];
        f16x4 hv;
        #pragma unroll
        for (int r=0;r<4;r++){
          float v = av[r];
          if (!edge) v = leakyf(v);
          hv[r] = (_Float16)v;
        }
        *(f16x4*)(hp + c2*16) = hv;
      }
    }
  }
}

// fix boundary voxels of fp16 H in place (proven wrapped-tap semantics, x-skip)
__global__ void k_corrH(_Float16* __restrict__ H, const _Float16* __restrict__ Xg,
                        const _Float16* __restrict__ Wh){
  int t = blockIdx.x*256 + threadIdx.x;            // 654336
  int co = t & 31; int t2 = t >> 5;
  int e = t2 % 284; int x = t2 / 284;
  int y, z;
  if (e < 72){ y = 0; z = e; }
  else if (e < 144){ y = 71; z = e - 72; }
  else if (e < 214){ z = 0; y = e - 143; }
  else { z = 71; y = e - 213; }
  int q = y*72 + z;
  float corr = 0.f;
  for (int tap=0; tap<27; tap++){
    int dx = tap/9, rr = tap%9, dy = rr/3, dz = rr%3;
    int xx = x + dx - 1;
    if ((unsigned)xx >= 72u) continue;
    int yy = y + dy - 1, zz = z + dz - 1;
    if ((unsigned)yy < 72u && (unsigned)zz < 72u) continue;
    int lin = (xx*5184 + q + (dy-1)*72 + (dz-1))*32;
    const _Float16* V = Xg + lin;
    const _Float16* Wr = Wh + (tap*32 + co)*32;
    float s = 0.f;
    #pragma unroll
    for (int ci=0; ci<32; ci++) s += (float)V[ci]*(float)Wr[ci];
    corr += s;
  }
  size_t idx = ((size_t)x*5184 + q)*32 + co;
  float v = (float)H[idx] - corr;
  v = leakyf(v);
  H[idx] = (_Float16)v;
}

// fix boundary voxels (fp32 final output path, fp16 residuals)
__global__ void k_corr(float* __restrict__ OUT, const _Float16* __restrict__ Xg,
                       const _Float16* __restrict__ Wh, const _Float16* __restrict__ X1h,
                       const _Float16* __restrict__ XresH, int mode2, int do_leaky){
  int t = blockIdx.x*256 + threadIdx.x;            // 654336
  int co = t & 31; int t2 = t >> 5;
  int e = t2 % 284; int x = t2 / 284;
  int y, z;
  if (e < 72){ y = 0; z = e; }
  else if (e < 144){ y = 71; z = e - 72; }
  else if (e < 214){ z = 0; y = e - 143; }
  else { z = 71; y = e - 213; }
  int q = y*72 + z;
  float corr = 0.f;
  for (int tap=0; tap<27; tap++){
    int dx = tap/9, rr = tap%9, dy = rr/3, dz = rr%3;
    int xx = x + dx - 1;
    if ((unsigned)xx >= 72u) continue;
    int yy = y + dy - 1, zz = z + dz - 1;
    if ((unsigned)yy < 72u && (unsigned)zz < 72u) continue;
    int lin = (xx*5184 + q + (dy-1)*72 + (dz-1))*32;
    const _Float16* V = Xg + lin;
    const _Float16* Wr = Wh + (tap*32 + co)*32;
    float s = 0.f;
    #pragma unroll
    for (int ci=0; ci<32; ci++) s += (float)V[ci]*(float)Wr[ci];
    corr += s;
  }
  size_t idx = (size_t)co*NS3 + (size_t)x*5184 + q;
  float v = OUT[idx] - corr;
  if (mode2) v += (float)X1h[idx] + (float)XresH[((size_t)x*5184 + q)*32 + co];
  if (do_leaky) v = leakyf(v);
  OUT[idx] = v;
}

// crop to 64^3, fc1 (32->128) + leaky + fc2 (128->6); 2 voxels/thread.
// All weights via wave-uniform scalar loads (w1t transposed [j][c]) -- no LDS.
__global__ void k_head(const float* __restrict__ X, const float* __restrict__ w1t, const float* __restrict__ b1,
                       const float* __restrict__ w2, const float* __restrict__ b2, float* __restrict__ out){
  int tid = threadIdx.x;
  int p0 = blockIdx.x*256 + tid;                   // [0, 131072)
  float xin[2][32];
  float acc[2][6];
  float bb2[6];
  #pragma unroll
  for (int o=0;o<6;o++) bb2[o] = b2[o];
  #pragma unroll
  for (int vv=0; vv<2; vv++){
    int p = p0 + vv*131072;
    int z = p % 64; int t = p / 64; int y = t % 64; int x = t / 64;
    size_t q = ((size_t)x*NS + y)*NS + z;
    #pragma unroll
    for (int c=0;c<32;c++) xin[vv][c] = X[(size_t)c*NS3 + q];
    #pragma unroll
    for (int o=0;o<6;o++) acc[vv][o]=bb2[o];
  }
  for (int j=0;j<128;j++){
    const float4* wj = (const float4*)(w1t + j*32);
    float h0 = b1[j], h1 = h0;
    #pragma unroll
    for (int c4=0;c4<8;c4++){
      float4 w = wj[c4];
      h0 += xin[0][c4*4+0]*w.x + xin[0][c4*4+1]*w.y + xin[0][c4*4+2]*w.z + xin[0][c4*4+3]*w.w;
      h1 += xin[1][c4*4+0]*w.x + xin[1][c4*4+1]*w.y + xin[1][c4*4+2]*w.z + xin[1][c4*4+3]*w.w;
    }
    h0 = leakyf(h0); h1 = leakyf(h1);
    const float* s2j = w2 + j*6;
    #pragma unroll
    for (int o=0;o<6;o++){
      float wv = s2j[o];
      acc[0][o] += h0*wv;
      acc[1][o] += h1*wv;
    }
  }
  #pragma unroll
  for (int vv=0; vv<2; vv++){
    float* O = out + (size_t)(p0 + vv*131072)*6;
    #pragma unroll
    for (int o=0;o<6;o++) O[o]=acc[vv][o];
  }
}

extern "C" void kernel_launch(void* const* d_in, const int* in_sizes, int n_in,
                              void* d_out, int out_size, void* d_ws, size_t ws_size,
                              hipStream_t stream) {
  const float* yeex = (const float*)d_in[0];
  const float* yeey = (const float*)d_in[1];
  const float* yeez = (const float*)d_in[2];
  const float* fc0w = (const float*)d_in[3];
  const float* fc0b = (const float*)d_in[4];
  const float* specw= (const float*)d_in[5];
  const float* bw1  = (const float*)d_in[6];
  const float* bw2  = (const float*)d_in[7];
  const float* fc1w = (const float*)d_in[8];
  const float* fc1b = (const float*)d_in[9];
  const float* fc2w = (const float*)d_in[10];
  const float* fc2b = (const float*)d_in[11];
  float* out = (float*)d_out;
  float* ws  = (float*)d_ws;

  float*  P0 = ws;                                  // 11943936 floats
  float*  X1s = ws + 11943936;                      // X1h fp16 slot
  float*  P2 = ws + 23887872;
  float2* A  = (float2*)(ws + 35831808);            // spectral slots
  float2* B  = (float2*)(ws + 41140224);
  float2* Cf = (float2*)(ws + 46448640);
  float2* Df = (float2*)(ws + 51757056);
  float2* TW = (float2*)(ws + 57065472);
  float*  W1T = ws + 57065728;                      // 4096 floats (fc1 transposed)
  // freq-conv fp16 GEMM operands (overlay A/B slots; dead by conv phase)
  _Float16* Ah = (_Float16*)A;
  _Float16* Bg = (_Float16*)B;
  _Float16* X1h = (_Float16*)X1s;                   // fp16 spectral result
  // fp16 buffers for the spatial conv path (overlay spectral slots, used after invyz)
  _Float16* XhG = (_Float16*)(ws + 35831808) + 4096;  // guarded data ptr
  _Float16* HhG = (_Float16*)(ws + 41807872) + 4096;
  _Float16* WhA = (_Float16*)(ws + 47783936);         // 27648 fp16
  _Float16* WhB = (_Float16*)(ws + 47797760);

  float* curX = P0; float* curY = P2;

  k_tw<<<1,128,0,stream>>>(TW);
  k_wpackT<<<16,256,0,stream>>>(fc1w, W1T);
  k_fc0<<<46656,256,0,stream>>>(yeex,yeey,yeez,fc0w,fc0b,curX);
  for (int i=0;i<4;i++){
    k_zdft<<<648,256,0,stream>>>(curX, A, TW);
    k_ydft<<<648,256,0,stream>>>(A, B, TW);
    k_xdftL<<<512,256,0,stream>>>(B, Cf, TW);
    k_wpackh<<<16000,256,0,stream>>>(specw + (size_t)i*8*64*64*125, Ah);
    k_cpackh<<<5184,256,0,stream>>>(Cf, Bg);
    hipMemsetAsync(Df, 0, (size_t)1327104*8, stream);
    k_freqmfma2<<<256,512,0,stream>>>(Ah, Bg, (float*)Df);
    k_invx<<<648,256,0,stream>>>(Df, A, TW);
    k_invyz<<<648,256,0,stream>>>(A, X1h, TW);
    // conv phase (spectral scratch now dead; overlay with fp16 buffers)
    k_wcvt2<<<216,256,0,stream>>>(bw1 + (size_t)i*27648, bw2 + (size_t)i*27648, WhA, WhB);
    k_cvt16<<<1460,256,0,stream>>>(curX, XhG);
    k_zgH<<<4,256,0,stream>>>(HhG);
    k_convm<<<648,576,0,stream>>>(XhG, WhA, nullptr, HhG, nullptr, nullptr, 0, 1);
    k_corrH<<<2556,256,0,stream>>>(HhG, XhG, WhA);
    k_convm<<<648,576,0,stream>>>(HhG, WhB, curY, nullptr, X1h, XhG, 1, (i<3)?1:0);
    k_corr<<<2556,256,0,stream>>>(curY, HhG, WhB, X1h, XhG, 1, (i<3)?1:0);
    float* tmp = curX; curX = curY; curY = tmp;
  }
  k_head<<<512,256,0,stream>>>(curX, W1T, fc1b, fc2w, fc2b, out);
}

// Round 21
// 2088.331 us; speedup vs baseline: 1.0197x; 1.0197x over previous
//
#include <hip/hip_runtime.h>
#include <math.h>

#define NS 72
#define NS2 (NS*NS)          // 5184
#define NS3 (NS*NS*NS)       // 373248
#define MZ 8
#define LALPHA 0.05f
#define CSCALE (1.0f/256.0f)

typedef _Float16 f16x8 __attribute__((ext_vector_type(8)));
typedef _Float16 f16x4 __attribute__((ext_vector_type(4)));
typedef float f32x4 __attribute__((ext_vector_type(4)));

__device__ __forceinline__ float leakyf(float v){ return v > 0.f ? v : LALPHA*v; }

// octant regions: x0, nx, y0, ny  (kz always [0,8))
__constant__ int c_RX0[8] = {0,64,0,64, 8,0,8,64};
__constant__ int c_RNX[8] = {8,8,8,8, 56,8,56,8};
__constant__ int c_RY0[8] = {0,0,64,64, 0,8,64,8};
__constant__ int c_RNY[8] = {8,8,8,8, 8,56,8,56};
// fp16 B boxes: base (in elements), BY = ny+4
__constant__ int c_Bbase[8] = {0,1728,3456,5184, 6912,15552,24192,32832};
__constant__ int c_BY[8]    = {12,12,12,12, 12,60,12,60};

__global__ void k_tw(float2* tw){
  int t = threadIdx.x;
  if (t < NS){
    double th = (2.0*M_PI/72.0)*(double)t;
    tw[t] = make_float2((float)cos(th), (float)sin(th));
  }
}

// transpose fc1 weights to [j][c] once
__global__ void k_wpackT(const float* __restrict__ w1, float* __restrict__ w1t){
  int e = blockIdx.x*256 + threadIdx.x;            // 4096
  int j = e >> 5, c = e & 31;
  w1t[e] = w1[c*128 + j];
}

__global__ void k_fc0(const float* __restrict__ yx, const float* __restrict__ yy,
                      const float* __restrict__ yz, const float* __restrict__ w,
                      const float* __restrict__ b, float* __restrict__ X){
  int idx = blockIdx.x*256 + threadIdx.x;
  int z = idx % NS; int t = idx / NS; int y = t % NS; t /= NS; int x = t % NS; int c = t / NS;
  float v = 0.f;
  if (x < 64 && y < 64 && z < 64){
    int p = (x*64 + y)*64 + z;
    float i0 = yx[p], i1 = yy[p], i2 = yz[p];
    float gx = (float)x*(1.f/63.f), gy = (float)y*(1.f/63.f), gz = (float)z*(1.f/63.f);
    v = b[c] + i0*w[0*32+c] + i1*w[1*32+c] + i2*w[2*32+c]
             + gx*w[3*32+c] + gy*w[4*32+c] + gz*w[5*32+c];
  }
  X[idx] = v;
}

// ---------------- truncated DFT chain ----------------
__global__ void k_zdft(const float* __restrict__ X, float2* __restrict__ A, const float2* __restrict__ tw){
  __shared__ float2 stw[NS];
  int tid = threadIdx.x;
  if (tid < NS) stw[tid] = tw[tid];
  __syncthreads();
  int f = blockIdx.x*256 + tid;
  const float* row = X + (size_t)f*NS;
  float ar[MZ], ai[MZ]; int tk[MZ];
  #pragma unroll
  for (int k=0;k<MZ;k++){ ar[k]=0.f; ai[k]=0.f; tk[k]=0; }
  for (int z4=0; z4<NS; z4+=4){
    float4 v4 = *(const float4*)(row + z4);
    float vs[4] = {v4.x, v4.y, v4.z, v4.w};
    #pragma unroll
    for (int zz=0; zz<4; zz++){
      float v = vs[zz];
      #pragma unroll
      for (int k=0;k<MZ;k++){
        float2 w = stw[tk[k]];
        ar[k] += v*w.x;
        ai[k] -= v*w.y;
        tk[k] += k; if (tk[k] >= NS) tk[k] -= NS;
      }
    }
  }
  float2* o = A + (size_t)f*MZ;
  #pragma unroll
  for (int k=0;k<MZ;k++) o[k] = make_float2(ar[k], ai[k]);
}

__global__ void k_ydft(const float2* __restrict__ A, float2* __restrict__ B, const float2* __restrict__ tw){
  __shared__ float2 stw[NS];
  int tid = threadIdx.x;
  if (tid < NS) stw[tid] = tw[tid];
  __syncthreads();
  int f = blockIdx.x*256 + tid;
  int ky = f % NS; int cx = f / NS;
  const float2* in = A + (size_t)cx*NS*MZ;
  float ar[MZ], ai[MZ];
  #pragma unroll
  for (int k=0;k<MZ;k++){ ar[k]=0.f; ai[k]=0.f; }
  int t = 0;
  for (int y=0;y<NS;y++){
    float2 w = stw[t]; t += ky; if (t>=NS) t-=NS;
    const float2* iy = in + y*MZ;
    #pragma unroll
    for (int k=0;k<MZ;k++){
      float2 v = iy[k];
      ar[k] += v.x*w.x + v.y*w.y;
      ai[k] += v.y*w.x - v.x*w.y;
    }
  }
  float2* o = B + (size_t)f*MZ;
  #pragma unroll
  for (int k=0;k<MZ;k++) o[k] = make_float2(ar[k], ai[k]);
}

// x-DFT restricted to the L-frame (2048 (kx,ky) pairs), 4 modes per thread
__global__ void k_xdftL(const float2* __restrict__ B, float2* __restrict__ C, const float2* __restrict__ tw){
  __shared__ float2 stw[NS];
  int tid = threadIdx.x;
  if (tid < NS) stw[tid] = tw[tid];
  __syncthreads();
  int t = blockIdx.x*256 + tid;                    // 131072 = 32c * 2048l * 2h
  int h = t & 1; int t2 = t >> 1;
  int c = t2 >> 11; int l = t2 & 2047;
  int kx, ky;
  if (l < 576){ ky = l & 7; kx = l >> 3; }
  else if (l < 1152){ int e = l - 576; ky = 64 + (e & 7); kx = e >> 3; }
  else { int e = l - 1152; int kyi = e >> 4; int kxi = e & 15;
         ky = 8 + kyi; kx = (kxi < 8) ? kxi : 56 + kxi; }
  int k0 = h*4;
  const float2* in = B + ((size_t)c*NS2 + ky)*MZ + k0;
  float ar[4], ai[4];
  #pragma unroll
  for (int k=0;k<4;k++){ ar[k]=0.f; ai[k]=0.f; }
  int tt = 0;
  for (int x=0;x<NS;x++){
    float2 w = stw[tt]; tt += kx; if (tt>=NS) tt-=NS;
    const float2* ix = in + (size_t)x*NS*MZ;
    #pragma unroll
    for (int k=0;k<4;k++){
      float2 v = ix[k];
      ar[k] += v.x*w.x + v.y*w.y;
      ai[k] += v.y*w.x - v.x*w.y;
    }
  }
  float2* o = C + (((size_t)c*NS + kx)*NS + ky)*MZ + k0;
  #pragma unroll
  for (int k=0;k<4;k++) o[k] = make_float2(ar[k], ai[k]);
}

// spectral weights fp32 -> fp16 A[r][tap][o=64][i=64], A[o][i] = w[o][(i&1)*32 + (i>>1)]
__global__ void k_wpackh(const float* __restrict__ W, _Float16* __restrict__ Ah){
  int e = blockIdx.x*256 + threadIdx.x;            // 4,096,000
  int i = e & 63; int o = (e>>6) & 63;
  int t2 = e >> 12; int tap = t2 % 125; int r = t2 / 125;
  const float* wr = W + (size_t)r*64*64*125;
  Ah[e] = (_Float16)wr[((size_t)(o*64 + (i&1)*32 + (i>>1)))*125 + tap];
}

// C -> fp16 region boxes Bg[elem][64], halo zeros, scaled
__global__ void k_cpackh(const float2* __restrict__ C, _Float16* __restrict__ Bg){
  int g = blockIdx.x*256 + threadIdx.x;            // 1,327,104
  int ci = g & 31; int elem = g >> 5;
  int r = 0;
  #pragma unroll
  for (int k=1;k<8;k++) if (elem >= c_Bbase[k]) r = k;
  int el = elem - c_Bbase[r];
  int BY = c_BY[r];
  int q3 = el % 12; int tt = el / 12; int q2 = tt % BY; int q1 = tt / BY;
  int kxr = q1-2, kyr = q2-2, kzr = q3-2;
  float2 v = make_float2(0.f,0.f);
  if ((unsigned)kxr < (unsigned)c_RNX[r] && (unsigned)kyr < (unsigned)c_RNY[r] && (unsigned)kzr < 8u){
    v = C[(((size_t)ci*NS + (c_RX0[r]+kxr))*NS + (c_RY0[r]+kyr))*MZ + kzr];
  }
  _Float16* o = Bg + (size_t)elem*64 + 2*ci;
  o[0] = (_Float16)(v.x*CSCALE);
  o[1] = (_Float16)(v.y*CSCALE);
}

// freq conv MFMA with fused in-LDS K-split reduction.
__global__ __launch_bounds__(512) void k_freqmfma2(const _Float16* __restrict__ Ah,
                                                   const _Float16* __restrict__ Bg,
                                                   float* __restrict__ Df){
  __shared__ float sAcc[2][64*65];                 // 33.3 KB
  int tid = threadIdx.x;
  int orig = blockIdx.x;                           // [0,256)
  int b = (orig & 7)*32 + (orig >> 3);             // XCD chunk swizzle (8x32 exact)
  int r, til;
  if (b < 32){ r = b>>3; til = b&7; }
  else       { r = 4 + (b-32)/56; til = (b-32)%56; }
  int x0 = c_RX0[r], y0 = c_RY0[r], BY = c_BY[r];
  int q1, q2base;
  if (r==5 || r==7){ q1 = 2 + til/7; q2base = 2 + (til%7)*8; }
  else             { q1 = 2 + til;   q2base = 2; }
  int wv = tid >> 6;
  int lane = tid & 63;
  int l15 = lane & 15, kg = lane >> 4;
  int q2l = q2base + (l15>>3), q3l = 2 + (l15&7);
  const _Float16* Ar = Ah + (size_t)r*125*4096;
  const _Float16* Br = Bg + (size_t)c_Bbase[r]*64;
  int lb = q2l*12 + q3l;
  f32x4 acc[4][4];
  f32x4 zz = {0.f,0.f,0.f,0.f};
  #pragma unroll
  for (int m=0;m<4;m++)
    #pragma unroll
    for (int n=0;n<4;n++) acc[m][n] = zz;
  int t0 = wv*16;
  int t1 = t0+16 < 125 ? t0+16 : 125;
  for (int tt=t0; tt<t1; tt++){
    int td = tt/25; int rm = tt - td*25; int th = rm/5; int tz = rm - th*5;
    const _Float16* At = Ar + tt*4096;
    f16x8 a[4][2];
    #pragma unroll
    for (int mt=0;mt<4;mt++){
      a[mt][0] = *(const f16x8*)(At + (mt*16+l15)*64 + kg*8);
      a[mt][1] = *(const f16x8*)(At + (mt*16+l15)*64 + 32 + kg*8);
    }
    int ebase = (q1 + td - 2)*BY*12 + lb + (th-2)*12 + (tz-2);
    f16x8 bf[4][2];
    #pragma unroll
    for (int nt=0;nt<4;nt++){
      const _Float16* bp = Br + (size_t)(ebase + nt*24)*64 + kg*8;
      bf[nt][0] = *(const f16x8*)(bp);
      bf[nt][1] = *(const f16x8*)(bp + 32);
    }
    #pragma unroll
    for (int mt=0;mt<4;mt++)
      #pragma unroll
      for (int nt=0;nt<4;nt++){
        acc[mt][nt] = __builtin_amdgcn_mfma_f32_16x16x32_f16(a[mt][0], bf[nt][0], acc[mt][nt],0,0,0);
        acc[mt][nt] = __builtin_amdgcn_mfma_f32_16x16x32_f16(a[mt][1], bf[nt][1], acc[mt][nt],0,0,0);
      }
  }
  int hb = wv >> 2, ph = wv & 3;
  float* dst = sAcc[hb] + lane*65;
  for (int p=0; p<4; p++){
    if (ph == p){
      #pragma unroll
      for (int mt=0;mt<4;mt++)
        #pragma unroll
        for (int nt=0;nt<4;nt++){
          int e = mt*16 + nt*4;
          if (p == 0){
            dst[e+0] = acc[mt][nt][0]; dst[e+1] = acc[mt][nt][1];
            dst[e+2] = acc[mt][nt][2]; dst[e+3] = acc[mt][nt][3];
          } else {
            dst[e+0] += acc[mt][nt][0]; dst[e+1] += acc[mt][nt][1];
            dst[e+2] += acc[mt][nt][2]; dst[e+3] += acc[mt][nt][3];
          }
        }
    }
    __syncthreads();
  }
  int lane2 = tid & 63;
  int pr = tid >> 6;
  int mt = pr >> 1, ntb = (pr & 1)*2;
  int l15b = lane2 & 15, kgb = lane2 >> 4;
  int q2b = q2base + (l15b>>3), q3b = 2 + (l15b&7);
  int kx = x0 + q1 - 2;
  int kz = q3b - 2;
  const float* s0 = sAcc[0] + lane2*65;
  const float* s1 = sAcc[1] + lane2*65;
  #pragma unroll
  for (int dn=0; dn<2; dn++){
    int nt = ntb + dn;
    int ky = y0 + q2b + nt*2 - 2;
    #pragma unroll
    for (int rg=0; rg<4; rg++){
      int e = mt*16 + nt*4 + rg;
      int o = mt*16 + kgb*4 + rg;
      int co = o >> 1, reim = o & 1;
      Df[((((size_t)co*NS + kx)*NS + ky)*MZ + kz)*2 + reim] = (s0[e] + s1[e])*256.0f;
    }
  }
}

// inverse x-DFT with L-frame trimming. Thread map f = (ky slowest, c, x fastest)
__global__ void k_invx(const float2* __restrict__ D, float2* __restrict__ E, const float2* __restrict__ tw){
  __shared__ float2 stw[NS];
  int tid = threadIdx.x;
  if (tid < NS) stw[tid] = tw[tid];
  __syncthreads();
  int f = blockIdx.x*256 + tid;
  int ky = f / 2304; int rem = f - ky*2304;
  int c = rem / NS; int x = rem - c*NS;
  const float2* in = D + ((size_t)c*NS2 + ky)*MZ;
  float ar[MZ], ai[MZ];
  #pragma unroll
  for (int k=0;k<MZ;k++){ ar[k]=0.f; ai[k]=0.f; }
  if (ky >= 8 && ky < 64){
    int t = 0;
    for (int kx=0;kx<8;kx++){
      float2 w = stw[t]; t += x; if (t>=NS) t-=NS;
      const float2* ix = in + (size_t)kx*NS*MZ;
      #pragma unroll
      for (int k=0;k<MZ;k++){
        float2 v = ix[k];
        ar[k] += v.x*w.x - v.y*w.y;
        ai[k] += v.x*w.y + v.y*w.x;
      }
    }
    t = (64*x) % NS;
    for (int kx=64;kx<NS;kx++){
      float2 w = stw[t]; t += x; if (t>=NS) t-=NS;
      const float2* ix = in + (size_t)kx*NS*MZ;
      #pragma unroll
      for (int k=0;k<MZ;k++){
        float2 v = ix[k];
        ar[k] += v.x*w.x - v.y*w.y;
        ai[k] += v.x*w.y + v.y*w.x;
      }
    }
  } else {
    int t = 0;
    for (int kx=0;kx<NS;kx++){
      float2 w = stw[t]; t += x; if (t>=NS) t-=NS;
      const float2* ix = in + (size_t)kx*NS*MZ;
      #pragma unroll
      for (int k=0;k<MZ;k++){
        float2 v = ix[k];
        ar[k] += v.x*w.x - v.y*w.y;
        ai[k] += v.x*w.y + v.y*w.x;
      }
    }
  }
  float2* o = E + (((size_t)c*NS + x)*NS + ky)*MZ;
  #pragma unroll
  for (int k=0;k<MZ;k++) o[k] = make_float2(ar[k]*(1.f/72.f), ai[k]*(1.f/72.f));
}

// fused invy+invz, writing fp16 X1h (channel-major [c][x][y][z]), f16x4 stores
__global__ void k_invyz(const float2* __restrict__ E, _Float16* __restrict__ X1h, const float2* __restrict__ tw){
  __shared__ float2 stw[NS];
  int tid = threadIdx.x;
  if (tid < NS) stw[tid] = tw[tid];
  __syncthreads();
  int f = blockIdx.x*256 + tid;
  int y = f % NS; int t2 = f / NS; int x = t2 % NS; int c = t2 / NS;
  const float2* in = E + ((size_t)c*NS + x)*NS*MZ;
  float ar[MZ], ai[MZ];
  #pragma unroll
  for (int k=0;k<MZ;k++){ ar[k]=0.f; ai[k]=0.f; }
  int t = 0;
  for (int ky=0;ky<NS;ky++){
    float2 w = stw[t]; t += y; if (t>=NS) t-=NS;
    const float2* ik = in + ky*MZ;
    #pragma unroll
    for (int k=0;k<MZ;k++){
      float2 v = ik[k];
      ar[k] += v.x*w.x - v.y*w.y;
      ai[k] += v.x*w.y + v.y*w.x;
    }
  }
  const float scale = 1.f/(72.f*72.f);
  _Float16* o = X1h + (size_t)f*NS;
  int tk[MZ];
  #pragma unroll
  for (int k=0;k<MZ;k++) tk[k]=0;
  for (int z4=0; z4<NS; z4+=4){
    f16x4 hv;
    #pragma unroll
    for (int zz=0; zz<4; zz++){
      float acc = ar[0];
      #pragma unroll
      for (int k=1;k<MZ;k++){
        float2 w = stw[tk[k]];
        acc += 2.f*(ar[k]*w.x - ai[k]*w.y);
        tk[k] += k; if (tk[k] >= NS) tk[k] -= NS;
      }
      hv[zz] = (_Float16)(acc*scale);
    }
    *(f16x4*)(o + z4) = hv;
  }
}

// ---------------- fp16 MFMA conv path ----------------

// both conv weights fp32 [co][ci][27] -> fp16 [tap][co][ci]
__global__ void k_wcvt2(const float* __restrict__ w1, const float* __restrict__ w2,
                        _Float16* __restrict__ WhA, _Float16* __restrict__ WhB){
  int e = blockIdx.x*256 + threadIdx.x;            // 55296
  int h = e >= 27648; int e2 = e - (h ? 27648 : 0);
  int tap = e2 >> 10; int co = (e2>>5)&31; int ci = e2&31;
  const float* w = h ? w2 : w1;
  _Float16* o = h ? WhB : WhA;
  o[e2] = (_Float16)w[(co*32+ci)*27 + tap];
}

// fp32 [c][p] -> fp16 channel-last [p][c]; blocks 1458,1459 zero the X +/-4096
// guards; blocks 1460,1461 zero the H guards (fused former k_zgH).
__global__ void k_cvt16(const float* __restrict__ Xf, _Float16* __restrict__ Xg,
                        _Float16* __restrict__ Hg){
  int b = blockIdx.x;
  int tid = threadIdx.x;
  if (b >= 1458){
    _Float16* g;
    if      (b == 1458) g = Xg - 4096;
    else if (b == 1459) g = Xg + (size_t)NS3*32;
    else if (b == 1460) g = Hg - 4096;
    else                g = Hg + (size_t)NS3*32;
    f16x8 zz = {0,0,0,0,0,0,0,0};
    f16x8* gp = (f16x8*)g;
    gp[tid] = zz; gp[tid+256] = zz;
    return;
  }
  int p = b*256 + tid;
  f16x8 o0,o1,o2,o3;
  #pragma unroll
  for (int c=0;c<8;c++){
    o0[c] = (_Float16)Xf[(size_t)c*NS3 + p];
    o1[c] = (_Float16)Xf[(size_t)(c+8)*NS3 + p];
    o2[c] = (_Float16)Xf[(size_t)(c+16)*NS3 + p];
    o3[c] = (_Float16)Xf[(size_t)(c+24)*NS3 + p];
  }
  f16x8* op = (f16x8*)(Xg + (size_t)p*32);
  op[0]=o0; op[1]=o1; op[2]=o2; op[3]=o3;
}

// implicit-GEMM conv via mfma_f32_16x16x32_f16 with LDS-staged B operand and
// XOR chunk-swizzle (pos ^= (row>>1)&3) breaking the 8-way read conflict.
// 1944 blocks x 192 threads (3 waves, 27 blocks/slab) -- best measured config.
// mode2=0: fp16 [p][c] OUTH. mode2=1: fp32 OUT with fp16 residuals.
__global__ __launch_bounds__(192) void k_convm(const _Float16* __restrict__ Xg,
    const _Float16* __restrict__ Wh, float* __restrict__ OUT, _Float16* __restrict__ OUTH,
    const _Float16* __restrict__ X1h, const _Float16* __restrict__ XresH,
    int mode2, int do_leaky){
  __shared__ _Float16 sB[338*32];                  // 21632 B
  int tid = threadIdx.x;
  int orig = blockIdx.x;                           // [0,1944)
  int xcd = orig & 7, loc = orig >> 3;
  int wg = xcd*243 + loc;
  int slab = wg/27, tb = wg - slab*27;
  int q0 = tb*192;
  int wid = tid >> 6;
  int lane = tid & 63;
  int l15 = lane & 15, kg = lane >> 4;
  f32x4 acc[2][4];
  f32x4 zz = {0.f,0.f,0.f,0.f};
  #pragma unroll
  for (int a=0;a<2;a++)
    #pragma unroll
    for (int b=0;b<4;b++) acc[a][b] = zz;
  int wbase = l15*32 + kg*8;
  int lbase = wid*64 + 73 + l15;                   // LDS row base for this lane
  for (int dx=0; dx<3; dx++){
    int xx = slab + dx - 1;
    if ((unsigned)xx >= 72u) continue;             // slab is block-uniform
    __syncthreads();                               // protect previous window reads
    {
      const f16x8* src = (const f16x8*)(Xg + ((long long)xx*5184 + q0 - 73)*32);
      f16x8* dst = (f16x8*)sB;
      for (int e=tid; e<1352; e+=192){
        int es = (e & ~3) | ((e & 3) ^ ((e >> 3) & 3));
        dst[es] = src[e];
      }
    }
    __syncthreads();
    const _Float16* Wdx = Wh + dx*9216;
    #pragma unroll
    for (int t9=0; t9<9; t9++){
      int off = ((t9/3)-1)*72 + (t9%3) - 1;
      const _Float16* wp = Wdx + t9*1024 + wbase;
      f16x8 a0 = *(const f16x8*)(wp);
      f16x8 a1 = *(const f16x8*)(wp + 512);
      int rr = lbase + off;
      const _Float16* bb = sB + (((rr << 2) | (kg ^ ((rr >> 1) & 3)))*8);
      f16x8 b0 = *(const f16x8*)(bb);
      f16x8 b1 = *(const f16x8*)(bb + 512);
      f16x8 b2 = *(const f16x8*)(bb + 1024);
      f16x8 b3 = *(const f16x8*)(bb + 1536);
      acc[0][0] = __builtin_amdgcn_mfma_f32_16x16x32_f16(a0,b0,acc[0][0],0,0,0);
      acc[0][1] = __builtin_amdgcn_mfma_f32_16x16x32_f16(a0,b1,acc[0][1],0,0,0);
      acc[0][2] = __builtin_amdgcn_mfma_f32_16x16x32_f16(a0,b2,acc[0][2],0,0,0);
      acc[0][3] = __builtin_amdgcn_mfma_f32_16x16x32_f16(a0,b3,acc[0][3],0,0,0);
      acc[1][0] = __builtin_amdgcn_mfma_f32_16x16x32_f16(a1,b0,acc[1][0],0,0,0);
      acc[1][1] = __builtin_amdgcn_mfma_f32_16x16x32_f16(a1,b1,acc[1][1],0,0,0);
      acc[1][2] = __builtin_amdgcn_mfma_f32_16x16x32_f16(a1,b2,acc[1][2],0,0,0);
      acc[1][3] = __builtin_amdgcn_mfma_f32_16x16x32_f16(a1,b3,acc[1][3],0,0,0);
    }
  }
  int q0w = q0 + wid*64;
  if (mode2){
    #pragma unroll
    for (int nt=0; nt<4; nt++){
      int q = q0w + nt*16 + l15;
      int y = q/72, z = q - y*72;
      bool edge = (y==0)||(y==71)||(z==0)||(z==71);
      #pragma unroll
      for (int c2=0;c2<2;c2++){
        #pragma unroll
        for (int r=0;r<4;r++){
          int co = c2*16 + kg*4 + r;
          size_t idx = (size_t)co*NS3 + (size_t)slab*5184 + q;
          float v = acc[c2][nt][r];
          if (!edge){
            v += (float)X1h[idx] + (float)XresH[((size_t)slab*5184 + q)*32 + co];
            if (do_leaky) v = leakyf(v);
          }
          OUT[idx] = v;
        }
      }
    }
  } else {
    #pragma unroll
    for (int nt=0; nt<4; nt++){
      int q = q0w + nt*16 + l15;
      int y = q/72, z = q - y*72;
      bool edge = (y==0)||(y==71)||(z==0)||(z==71);
      _Float16* hp = OUTH + ((size_t)slab*5184 + q)*32 + kg*4;
      #pragma unroll
      for (int c2=0;c2<2;c2++){
        f32x4 av = acc[c2][nt];
        f16x4 hv;
        #pragma unroll
        for (int r=0;r<4;r++){
          float v = av[r];
          if (!edge) v = leakyf(v);
          hv[r] = (_Float16)v;
        }
        *(f16x4*)(hp + c2*16) = hv;
      }
    }
  }
}

// fix boundary voxels of fp16 H in place (proven wrapped-tap semantics, x-skip)
__global__ void k_corrH(_Float16* __restrict__ H, const _Float16* __restrict__ Xg,
                        const _Float16* __restrict__ Wh){
  int t = blockIdx.x*256 + threadIdx.x;            // 654336
  int co = t & 31; int t2 = t >> 5;
  int e = t2 % 284; int x = t2 / 284;
  int y, z;
  if (e < 72){ y = 0; z = e; }
  else if (e < 144){ y = 71; z = e - 72; }
  else if (e < 214){ z = 0; y = e - 143; }
  else { z = 71; y = e - 213; }
  int q = y*72 + z;
  float corr = 0.f;
  for (int tap=0; tap<27; tap++){
    int dx = tap/9, rr = tap%9, dy = rr/3, dz = rr%3;
    int xx = x + dx - 1;
    if ((unsigned)xx >= 72u) continue;
    int yy = y + dy - 1, zz = z + dz - 1;
    if ((unsigned)yy < 72u && (unsigned)zz < 72u) continue;
    int lin = (xx*5184 + q + (dy-1)*72 + (dz-1))*32;
    const _Float16* V = Xg + lin;
    const _Float16* Wr = Wh + (tap*32 + co)*32;
    float s = 0.f;
    #pragma unroll
    for (int ci=0; ci<32; ci++) s += (float)V[ci]*(float)Wr[ci];
    corr += s;
  }
  size_t idx = ((size_t)x*5184 + q)*32 + co;
  float v = (float)H[idx] - corr;
  v = leakyf(v);
  H[idx] = (_Float16)v;
}

// fix boundary voxels (fp32 final output path, fp16 residuals)
__global__ void k_corr(float* __restrict__ OUT, const _Float16* __restrict__ Xg,
                       const _Float16* __restrict__ Wh, const _Float16* __restrict__ X1h,
                       const _Float16* __restrict__ XresH, int mode2, int do_leaky){
  int t = blockIdx.x*256 + threadIdx.x;            // 654336
  int co = t & 31; int t2 = t >> 5;
  int e = t2 % 284; int x = t2 / 284;
  int y, z;
  if (e < 72){ y = 0; z = e; }
  else if (e < 144){ y = 71; z = e - 72; }
  else if (e < 214){ z = 0; y = e - 143; }
  else { z = 71; y = e - 213; }
  int q = y*72 + z;
  float corr = 0.f;
  for (int tap=0; tap<27; tap++){
    int dx = tap/9, rr = tap%9, dy = rr/3, dz = rr%3;
    int xx = x + dx - 1;
    if ((unsigned)xx >= 72u) continue;
    int yy = y + dy - 1, zz = z + dz - 1;
    if ((unsigned)yy < 72u && (unsigned)zz < 72u) continue;
    int lin = (xx*5184 + q + (dy-1)*72 + (dz-1))*32;
    const _Float16* V = Xg + lin;
    const _Float16* Wr = Wh + (tap*32 + co)*32;
    float s = 0.f;
    #pragma unroll
    for (int ci=0; ci<32; ci++) s += (float)V[ci]*(float)Wr[ci];
    corr += s;
  }
  size_t idx = (size_t)co*NS3 + (size_t)x*5184 + q;
  float v = OUT[idx] - corr;
  if (mode2) v += (float)X1h[idx] + (float)XresH[((size_t)x*5184 + q)*32 + co];
  if (do_leaky) v = leakyf(v);
  OUT[idx] = v;
}

// crop to 64^3, fc1 (32->128) + leaky + fc2 (128->6); 2 voxels/thread.
// All weights via wave-uniform scalar loads (w1t transposed [j][c]) -- no LDS.
__global__ void k_head(const float* __restrict__ X, const float* __restrict__ w1t, const float* __restrict__ b1,
                       const float* __restrict__ w2, const float* __restrict__ b2, float* __restrict__ out){
  int tid = threadIdx.x;
  int p0 = blockIdx.x*256 + tid;                   // [0, 131072)
  float xin[2][32];
  float acc[2][6];
  float bb2[6];
  #pragma unroll
  for (int o=0;o<6;o++) bb2[o] = b2[o];
  #pragma unroll
  for (int vv=0; vv<2; vv++){
    int p = p0 + vv*131072;
    int z = p % 64; int t = p / 64; int y = t % 64; int x = t / 64;
    size_t q = ((size_t)x*NS + y)*NS + z;
    #pragma unroll
    for (int c=0;c<32;c++) xin[vv][c] = X[(size_t)c*NS3 + q];
    #pragma unroll
    for (int o=0;o<6;o++) acc[vv][o]=bb2[o];
  }
  for (int j=0;j<128;j++){
    const float4* wj = (const float4*)(w1t + j*32);
    float h0 = b1[j], h1 = h0;
    #pragma unroll
    for (int c4=0;c4<8;c4++){
      float4 w = wj[c4];
      h0 += xin[0][c4*4+0]*w.x + xin[0][c4*4+1]*w.y + xin[0][c4*4+2]*w.z + xin[0][c4*4+3]*w.w;
      h1 += xin[1][c4*4+0]*w.x + xin[1][c4*4+1]*w.y + xin[1][c4*4+2]*w.z + xin[1][c4*4+3]*w.w;
    }
    h0 = leakyf(h0); h1 = leakyf(h1);
    const float* s2j = w2 + j*6;
    #pragma unroll
    for (int o=0;o<6;o++){
      float wv = s2j[o];
      acc[0][o] += h0*wv;
      acc[1][o] += h1*wv;
    }
  }
  #pragma unroll
  for (int vv=0; vv<2; vv++){
    float* O = out + (size_t)(p0 + vv*131072)*6;
    #pragma unroll
    for (int o=0;o<6;o++) O[o]=acc[vv][o];
  }
}

extern "C" void kernel_launch(void* const* d_in, const int* in_sizes, int n_in,
                              void* d_out, int out_size, void* d_ws, size_t ws_size,
                              hipStream_t stream) {
  const float* yeex = (const float*)d_in[0];
  const float* yeey = (const float*)d_in[1];
  const float* yeez = (const float*)d_in[2];
  const float* fc0w = (const float*)d_in[3];
  const float* fc0b = (const float*)d_in[4];
  const float* specw= (const float*)d_in[5];
  const float* bw1  = (const float*)d_in[6];
  const float* bw2  = (const float*)d_in[7];
  const float* fc1w = (const float*)d_in[8];
  const float* fc1b = (const float*)d_in[9];
  const float* fc2w = (const float*)d_in[10];
  const float* fc2b = (const float*)d_in[11];
  float* out = (float*)d_out;
  float* ws  = (float*)d_ws;

  float*  P0 = ws;                                  // 11943936 floats
  float*  X1s = ws + 11943936;                      // X1h fp16 slot
  float*  P2 = ws + 23887872;
  float2* A  = (float2*)(ws + 35831808);            // spectral slots
  float2* B  = (float2*)(ws + 41140224);
  float2* Cf = (float2*)(ws + 46448640);
  float2* Df = (float2*)(ws + 51757056);
  float2* TW = (float2*)(ws + 57065472);
  float*  W1T = ws + 57065728;                      // 4096 floats (fc1 transposed)
  // freq-conv fp16 GEMM operands (overlay A/B slots; dead by conv phase)
  _Float16* Ah = (_Float16*)A;
  _Float16* Bg = (_Float16*)B;
  _Float16* X1h = (_Float16*)X1s;                   // fp16 spectral result
  // fp16 buffers for the spatial conv path (overlay spectral slots, used after invyz)
  _Float16* XhG = (_Float16*)(ws + 35831808) + 4096;  // guarded data ptr
  _Float16* HhG = (_Float16*)(ws + 41807872) + 4096;
  _Float16* WhA = (_Float16*)(ws + 47783936);         // 27648 fp16
  _Float16* WhB = (_Float16*)(ws + 47797760);

  float* curX = P0; float* curY = P2;

  k_tw<<<1,128,0,stream>>>(TW);
  k_wpackT<<<16,256,0,stream>>>(fc1w, W1T);
  k_fc0<<<46656,256,0,stream>>>(yeex,yeey,yeez,fc0w,fc0b,curX);
  for (int i=0;i<4;i++){
    k_zdft<<<648,256,0,stream>>>(curX, A, TW);
    k_ydft<<<648,256,0,stream>>>(A, B, TW);
    k_xdftL<<<512,256,0,stream>>>(B, Cf, TW);
    k_wpackh<<<16000,256,0,stream>>>(specw + (size_t)i*8*64*64*125, Ah);
    k_cpackh<<<5184,256,0,stream>>>(Cf, Bg);
    hipMemsetAsync(Df, 0, (size_t)1327104*8, stream);
    k_freqmfma2<<<256,512,0,stream>>>(Ah, Bg, (float*)Df);
    k_invx<<<648,256,0,stream>>>(Df, A, TW);
    k_invyz<<<648,256,0,stream>>>(A, X1h, TW);
    // conv phase (spectral scratch now dead; overlay with fp16 buffers)
    k_wcvt2<<<216,256,0,stream>>>(bw1 + (size_t)i*27648, bw2 + (size_t)i*27648, WhA, WhB);
    k_cvt16<<<1462,256,0,stream>>>(curX, XhG, HhG);
    k_convm<<<1944,192,0,stream>>>(XhG, WhA, nullptr, HhG, nullptr, nullptr, 0, 1);
    k_corrH<<<2556,256,0,stream>>>(HhG, XhG, WhA);
    k_convm<<<1944,192,0,stream>>>(HhG, WhB, curY, nullptr, X1h, XhG, 1, (i<3)?1:0);
    k_corr<<<2556,256,0,stream>>>(curY, HhG, WhB, X1h, XhG, 1, (i<3)?1:0);
    float* tmp = curX; curX = curY; curY = tmp;
  }
  k_head<<<512,256,0,stream>>>(curX, W1T, fc1b, fc2w, fc2b, out);
}

// Round 22
// 2069.308 us; speedup vs baseline: 1.0290x; 1.0092x over previous
//
#include <hip/hip_runtime.h>
#include <math.h>

#define NS 72
#define NS2 (NS*NS)          // 5184
#define NS3 (NS*NS*NS)       // 373248
#define MZ 8
#define LALPHA 0.05f
#define CSCALE (1.0f/256.0f)

typedef _Float16 f16x8 __attribute__((ext_vector_type(8)));
typedef _Float16 f16x4 __attribute__((ext_vector_type(4)));
typedef float f32x4 __attribute__((ext_vector_type(4)));

__device__ __forceinline__ float leakyf(float v){ return v > 0.f ? v : LALPHA*v; }

// octant regions: x0, nx, y0, ny  (kz always [0,8))
__constant__ int c_RX0[8] = {0,64,0,64, 8,0,8,64};
__constant__ int c_RNX[8] = {8,8,8,8, 56,8,56,8};
__constant__ int c_RY0[8] = {0,0,64,64, 0,8,64,8};
__constant__ int c_RNY[8] = {8,8,8,8, 8,56,8,56};
// fp16 B boxes: base (in elements), BY = ny+4
__constant__ int c_Bbase[8] = {0,1728,3456,5184, 6912,15552,24192,32832};
__constant__ int c_BY[8]    = {12,12,12,12, 12,60,12,60};

__global__ void k_tw(float2* tw){
  int t = threadIdx.x;
  if (t < NS){
    double th = (2.0*M_PI/72.0)*(double)t;
    tw[t] = make_float2((float)cos(th), (float)sin(th));
  }
}

// transpose fc1 weights to [j][c] once
__global__ void k_wpackT(const float* __restrict__ w1, float* __restrict__ w1t){
  int e = blockIdx.x*256 + threadIdx.x;            // 4096
  int j = e >> 5, c = e & 31;
  w1t[e] = w1[c*128 + j];
}

__global__ void k_fc0(const float* __restrict__ yx, const float* __restrict__ yy,
                      const float* __restrict__ yz, const float* __restrict__ w,
                      const float* __restrict__ b, float* __restrict__ X){
  int idx = blockIdx.x*256 + threadIdx.x;
  int z = idx % NS; int t = idx / NS; int y = t % NS; t /= NS; int x = t % NS; int c = t / NS;
  float v = 0.f;
  if (x < 64 && y < 64 && z < 64){
    int p = (x*64 + y)*64 + z;
    float i0 = yx[p], i1 = yy[p], i2 = yz[p];
    float gx = (float)x*(1.f/63.f), gy = (float)y*(1.f/63.f), gz = (float)z*(1.f/63.f);
    v = b[c] + i0*w[0*32+c] + i1*w[1*32+c] + i2*w[2*32+c]
             + gx*w[3*32+c] + gy*w[4*32+c] + gz*w[5*32+c];
  }
  X[idx] = v;
}

// ---------------- truncated DFT chain ----------------
__global__ void k_zdft(const float* __restrict__ X, float2* __restrict__ A, const float2* __restrict__ tw){
  __shared__ float2 stw[NS];
  int tid = threadIdx.x;
  if (tid < NS) stw[tid] = tw[tid];
  __syncthreads();
  int f = blockIdx.x*256 + tid;
  const float* row = X + (size_t)f*NS;
  float ar[MZ], ai[MZ]; int tk[MZ];
  #pragma unroll
  for (int k=0;k<MZ;k++){ ar[k]=0.f; ai[k]=0.f; tk[k]=0; }
  for (int z4=0; z4<NS; z4+=4){
    float4 v4 = *(const float4*)(row + z4);
    float vs[4] = {v4.x, v4.y, v4.z, v4.w};
    #pragma unroll
    for (int zz=0; zz<4; zz++){
      float v = vs[zz];
      #pragma unroll
      for (int k=0;k<MZ;k++){
        float2 w = stw[tk[k]];
        ar[k] += v*w.x;
        ai[k] -= v*w.y;
        tk[k] += k; if (tk[k] >= NS) tk[k] -= NS;
      }
    }
  }
  float2* o = A + (size_t)f*MZ;
  #pragma unroll
  for (int k=0;k<MZ;k++) o[k] = make_float2(ar[k], ai[k]);
}

__global__ void k_ydft(const float2* __restrict__ A, float2* __restrict__ B, const float2* __restrict__ tw){
  __shared__ float2 stw[NS];
  int tid = threadIdx.x;
  if (tid < NS) stw[tid] = tw[tid];
  __syncthreads();
  int f = blockIdx.x*256 + tid;
  int ky = f % NS; int cx = f / NS;
  const float2* in = A + (size_t)cx*NS*MZ;
  float ar[MZ], ai[MZ];
  #pragma unroll
  for (int k=0;k<MZ;k++){ ar[k]=0.f; ai[k]=0.f; }
  int t = 0;
  for (int y=0;y<NS;y++){
    float2 w = stw[t]; t += ky; if (t>=NS) t-=NS;
    const float2* iy = in + y*MZ;
    #pragma unroll
    for (int k=0;k<MZ;k++){
      float2 v = iy[k];
      ar[k] += v.x*w.x + v.y*w.y;
      ai[k] += v.y*w.x - v.x*w.y;
    }
  }
  float2* o = B + (size_t)f*MZ;
  #pragma unroll
  for (int k=0;k<MZ;k++) o[k] = make_float2(ar[k], ai[k]);
}

// x-DFT restricted to the L-frame (2048 (kx,ky) pairs), 4 modes per thread
__global__ void k_xdftL(const float2* __restrict__ B, float2* __restrict__ C, const float2* __restrict__ tw){
  __shared__ float2 stw[NS];
  int tid = threadIdx.x;
  if (tid < NS) stw[tid] = tw[tid];
  __syncthreads();
  int t = blockIdx.x*256 + tid;                    // 131072 = 32c * 2048l * 2h
  int h = t & 1; int t2 = t >> 1;
  int c = t2 >> 11; int l = t2 & 2047;
  int kx, ky;
  if (l < 576){ ky = l & 7; kx = l >> 3; }
  else if (l < 1152){ int e = l - 576; ky = 64 + (e & 7); kx = e >> 3; }
  else { int e = l - 1152; int kyi = e >> 4; int kxi = e & 15;
         ky = 8 + kyi; kx = (kxi < 8) ? kxi : 56 + kxi; }
  int k0 = h*4;
  const float2* in = B + ((size_t)c*NS2 + ky)*MZ + k0;
  float ar[4], ai[4];
  #pragma unroll
  for (int k=0;k<4;k++){ ar[k]=0.f; ai[k]=0.f; }
  int tt = 0;
  for (int x=0;x<NS;x++){
    float2 w = stw[tt]; tt += kx; if (tt>=NS) tt-=NS;
    const float2* ix = in + (size_t)x*NS*MZ;
    #pragma unroll
    for (int k=0;k<4;k++){
      float2 v = ix[k];
      ar[k] += v.x*w.x + v.y*w.y;
      ai[k] += v.y*w.x - v.x*w.y;
    }
  }
  float2* o = C + (((size_t)c*NS + kx)*NS + ky)*MZ + k0;
  #pragma unroll
  for (int k=0;k<4;k++) o[k] = make_float2(ar[k], ai[k]);
}

// merged spectral packing: blocks [0,16000) = weights fp32->fp16 A-layout;
// blocks [16000,21184) = C -> fp16 region boxes Bg (halo zeros, scaled)
__global__ void k_pack(const float* __restrict__ W, _Float16* __restrict__ Ah,
                       const float2* __restrict__ C, _Float16* __restrict__ Bg){
  int b = blockIdx.x;
  int tid = threadIdx.x;
  if (b < 16000){
    int e = b*256 + tid;                           // 4,096,000
    int i = e & 63; int o = (e>>6) & 63;
    int t2 = e >> 12; int tap = t2 % 125; int r = t2 / 125;
    const float* wr = W + (size_t)r*64*64*125;
    Ah[e] = (_Float16)wr[((size_t)(o*64 + (i&1)*32 + (i>>1)))*125 + tap];
  } else {
    int g = (b-16000)*256 + tid;                   // 1,327,104
    int ci = g & 31; int elem = g >> 5;
    int r = 0;
    #pragma unroll
    for (int k=1;k<8;k++) if (elem >= c_Bbase[k]) r = k;
    int el = elem - c_Bbase[r];
    int BY = c_BY[r];
    int q3 = el % 12; int tt = el / 12; int q2 = tt % BY; int q1 = tt / BY;
    int kxr = q1-2, kyr = q2-2, kzr = q3-2;
    float2 v = make_float2(0.f,0.f);
    if ((unsigned)kxr < (unsigned)c_RNX[r] && (unsigned)kyr < (unsigned)c_RNY[r] && (unsigned)kzr < 8u){
      v = C[(((size_t)ci*NS + (c_RX0[r]+kxr))*NS + (c_RY0[r]+kyr))*MZ + kzr];
    }
    _Float16* o = Bg + (size_t)elem*64 + 2*ci;
    o[0] = (_Float16)(v.x*CSCALE);
    o[1] = (_Float16)(v.y*CSCALE);
  }
}

// freq conv MFMA with fused in-LDS K-split reduction.
__global__ __launch_bounds__(512) void k_freqmfma2(const _Float16* __restrict__ Ah,
                                                   const _Float16* __restrict__ Bg,
                                                   float* __restrict__ Df){
  __shared__ float sAcc[2][64*65];                 // 33.3 KB
  int tid = threadIdx.x;
  int orig = blockIdx.x;                           // [0,256)
  int b = (orig & 7)*32 + (orig >> 3);             // XCD chunk swizzle (8x32 exact)
  int r, til;
  if (b < 32){ r = b>>3; til = b&7; }
  else       { r = 4 + (b-32)/56; til = (b-32)%56; }
  int x0 = c_RX0[r], y0 = c_RY0[r], BY = c_BY[r];
  int q1, q2base;
  if (r==5 || r==7){ q1 = 2 + til/7; q2base = 2 + (til%7)*8; }
  else             { q1 = 2 + til;   q2base = 2; }
  int wv = tid >> 6;
  int lane = tid & 63;
  int l15 = lane & 15, kg = lane >> 4;
  int q2l = q2base + (l15>>3), q3l = 2 + (l15&7);
  const _Float16* Ar = Ah + (size_t)r*125*4096;
  const _Float16* Br = Bg + (size_t)c_Bbase[r]*64;
  int lb = q2l*12 + q3l;
  f32x4 acc[4][4];
  f32x4 zz = {0.f,0.f,0.f,0.f};
  #pragma unroll
  for (int m=0;m<4;m++)
    #pragma unroll
    for (int n=0;n<4;n++) acc[m][n] = zz;
  int t0 = wv*16;
  int t1 = t0+16 < 125 ? t0+16 : 125;
  for (int tt=t0; tt<t1; tt++){
    int td = tt/25; int rm = tt - td*25; int th = rm/5; int tz = rm - th*5;
    const _Float16* At = Ar + tt*4096;
    f16x8 a[4][2];
    #pragma unroll
    for (int mt=0;mt<4;mt++){
      a[mt][0] = *(const f16x8*)(At + (mt*16+l15)*64 + kg*8);
      a[mt][1] = *(const f16x8*)(At + (mt*16+l15)*64 + 32 + kg*8);
    }
    int ebase = (q1 + td - 2)*BY*12 + lb + (th-2)*12 + (tz-2);
    f16x8 bf[4][2];
    #pragma unroll
    for (int nt=0;nt<4;nt++){
      const _Float16* bp = Br + (size_t)(ebase + nt*24)*64 + kg*8;
      bf[nt][0] = *(const f16x8*)(bp);
      bf[nt][1] = *(const f16x8*)(bp + 32);
    }
    #pragma unroll
    for (int mt=0;mt<4;mt++)
      #pragma unroll
      for (int nt=0;nt<4;nt++){
        acc[mt][nt] = __builtin_amdgcn_mfma_f32_16x16x32_f16(a[mt][0], bf[nt][0], acc[mt][nt],0,0,0);
        acc[mt][nt] = __builtin_amdgcn_mfma_f32_16x16x32_f16(a[mt][1], bf[nt][1], acc[mt][nt],0,0,0);
      }
  }
  int hb = wv >> 2, ph = wv & 3;
  float* dst = sAcc[hb] + lane*65;
  for (int p=0; p<4; p++){
    if (ph == p){
      #pragma unroll
      for (int mt=0;mt<4;mt++)
        #pragma unroll
        for (int nt=0;nt<4;nt++){
          int e = mt*16 + nt*4;
          if (p == 0){
            dst[e+0] = acc[mt][nt][0]; dst[e+1] = acc[mt][nt][1];
            dst[e+2] = acc[mt][nt][2]; dst[e+3] = acc[mt][nt][3];
          } else {
            dst[e+0] += acc[mt][nt][0]; dst[e+1] += acc[mt][nt][1];
            dst[e+2] += acc[mt][nt][2]; dst[e+3] += acc[mt][nt][3];
          }
        }
    }
    __syncthreads();
  }
  int lane2 = tid & 63;
  int pr = tid >> 6;
  int mt = pr >> 1, ntb = (pr & 1)*2;
  int l15b = lane2 & 15, kgb = lane2 >> 4;
  int q2b = q2base + (l15b>>3), q3b = 2 + (l15b&7);
  int kx = x0 + q1 - 2;
  int kz = q3b - 2;
  const float* s0 = sAcc[0] + lane2*65;
  const float* s1 = sAcc[1] + lane2*65;
  #pragma unroll
  for (int dn=0; dn<2; dn++){
    int nt = ntb + dn;
    int ky = y0 + q2b + nt*2 - 2;
    #pragma unroll
    for (int rg=0; rg<4; rg++){
      int e = mt*16 + nt*4 + rg;
      int o = mt*16 + kgb*4 + rg;
      int co = o >> 1, reim = o & 1;
      Df[((((size_t)co*NS + kx)*NS + ky)*MZ + kz)*2 + reim] = (s0[e] + s1[e])*256.0f;
    }
  }
}

// inverse x-DFT with L-frame trimming. Thread map f = (ky slowest, c, x fastest)
__global__ void k_invx(const float2* __restrict__ D, float2* __restrict__ E, const float2* __restrict__ tw){
  __shared__ float2 stw[NS];
  int tid = threadIdx.x;
  if (tid < NS) stw[tid] = tw[tid];
  __syncthreads();
  int f = blockIdx.x*256 + tid;
  int ky = f / 2304; int rem = f - ky*2304;
  int c = rem / NS; int x = rem - c*NS;
  const float2* in = D + ((size_t)c*NS2 + ky)*MZ;
  float ar[MZ], ai[MZ];
  #pragma unroll
  for (int k=0;k<MZ;k++){ ar[k]=0.f; ai[k]=0.f; }
  if (ky >= 8 && ky < 64){
    int t = 0;
    for (int kx=0;kx<8;kx++){
      float2 w = stw[t]; t += x; if (t>=NS) t-=NS;
      const float2* ix = in + (size_t)kx*NS*MZ;
      #pragma unroll
      for (int k=0;k<MZ;k++){
        float2 v = ix[k];
        ar[k] += v.x*w.x - v.y*w.y;
        ai[k] += v.x*w.y + v.y*w.x;
      }
    }
    t = (64*x) % NS;
    for (int kx=64;kx<NS;kx++){
      float2 w = stw[t]; t += x; if (t>=NS) t-=NS;
      const float2* ix = in + (size_t)kx*NS*MZ;
      #pragma unroll
      for (int k=0;k<MZ;k++){
        float2 v = ix[k];
        ar[k] += v.x*w.x - v.y*w.y;
        ai[k] += v.x*w.y + v.y*w.x;
      }
    }
  } else {
    int t = 0;
    for (int kx=0;kx<NS;kx++){
      float2 w = stw[t]; t += x; if (t>=NS) t-=NS;
      const float2* ix = in + (size_t)kx*NS*MZ;
      #pragma unroll
      for (int k=0;k<MZ;k++){
        float2 v = ix[k];
        ar[k] += v.x*w.x - v.y*w.y;
        ai[k] += v.x*w.y + v.y*w.x;
      }
    }
  }
  float2* o = E + (((size_t)c*NS + x)*NS + ky)*MZ;
  #pragma unroll
  for (int k=0;k<MZ;k++) o[k] = make_float2(ar[k]*(1.f/72.f), ai[k]*(1.f/72.f));
}

// fused invy+invz, writing fp16 X1h (channel-major [c][x][y][z]), f16x4 stores
__global__ void k_invyz(const float2* __restrict__ E, _Float16* __restrict__ X1h, const float2* __restrict__ tw){
  __shared__ float2 stw[NS];
  int tid = threadIdx.x;
  if (tid < NS) stw[tid] = tw[tid];
  __syncthreads();
  int f = blockIdx.x*256 + tid;
  int y = f % NS; int t2 = f / NS; int x = t2 % NS; int c = t2 / NS;
  const float2* in = E + ((size_t)c*NS + x)*NS*MZ;
  float ar[MZ], ai[MZ];
  #pragma unroll
  for (int k=0;k<MZ;k++){ ar[k]=0.f; ai[k]=0.f; }
  int t = 0;
  for (int ky=0;ky<NS;ky++){
    float2 w = stw[t]; t += y; if (t>=NS) t-=NS;
    const float2* ik = in + ky*MZ;
    #pragma unroll
    for (int k=0;k<MZ;k++){
      float2 v = ik[k];
      ar[k] += v.x*w.x - v.y*w.y;
      ai[k] += v.x*w.y + v.y*w.x;
    }
  }
  const float scale = 1.f/(72.f*72.f);
  _Float16* o = X1h + (size_t)f*NS;
  int tk[MZ];
  #pragma unroll
  for (int k=0;k<MZ;k++) tk[k]=0;
  for (int z4=0; z4<NS; z4+=4){
    f16x4 hv;
    #pragma unroll
    for (int zz=0; zz<4; zz++){
      float acc = ar[0];
      #pragma unroll
      for (int k=1;k<MZ;k++){
        float2 w = stw[tk[k]];
        acc += 2.f*(ar[k]*w.x - ai[k]*w.y);
        tk[k] += k; if (tk[k] >= NS) tk[k] -= NS;
      }
      hv[zz] = (_Float16)(acc*scale);
    }
    *(f16x4*)(o + z4) = hv;
  }
}

// ---------------- fp16 MFMA conv path ----------------

// merged conversions: blocks [0,1458) fp32->fp16 channel-last data;
// blocks 1458..1461 zero X/H guards; blocks [1462,1678) both conv weights.
__global__ void k_cvtall(const float* __restrict__ Xf, _Float16* __restrict__ Xg,
                         _Float16* __restrict__ Hg,
                         const float* __restrict__ w1, const float* __restrict__ w2,
                         _Float16* __restrict__ WhA, _Float16* __restrict__ WhB){
  int b = blockIdx.x;
  int tid = threadIdx.x;
  if (b >= 1462){
    int e = (b-1462)*256 + tid;                    // 55296
    int h = e >= 27648; int e2 = e - (h ? 27648 : 0);
    int tap = e2 >> 10; int co = (e2>>5)&31; int ci = e2&31;
    const float* w = h ? w2 : w1;
    _Float16* o = h ? WhB : WhA;
    o[e2] = (_Float16)w[(co*32+ci)*27 + tap];
    return;
  }
  if (b >= 1458){
    _Float16* g;
    if      (b == 1458) g = Xg - 4096;
    else if (b == 1459) g = Xg + (size_t)NS3*32;
    else if (b == 1460) g = Hg - 4096;
    else                g = Hg + (size_t)NS3*32;
    f16x8 zz = {0,0,0,0,0,0,0,0};
    f16x8* gp = (f16x8*)g;
    gp[tid] = zz; gp[tid+256] = zz;
    return;
  }
  int p = b*256 + tid;
  f16x8 o0,o1,o2,o3;
  #pragma unroll
  for (int c=0;c<8;c++){
    o0[c] = (_Float16)Xf[(size_t)c*NS3 + p];
    o1[c] = (_Float16)Xf[(size_t)(c+8)*NS3 + p];
    o2[c] = (_Float16)Xf[(size_t)(c+16)*NS3 + p];
    o3[c] = (_Float16)Xf[(size_t)(c+24)*NS3 + p];
  }
  f16x8* op = (f16x8*)(Xg + (size_t)p*32);
  op[0]=o0; op[1]=o1; op[2]=o2; op[3]=o3;
}

// implicit-GEMM conv via mfma_f32_16x16x32_f16 with LDS-staged B operand and
// XOR chunk-swizzle (pos ^= (row>>1)&3) breaking the 8-way read conflict.
// 1944 blocks x 192 threads (3 waves, 27 blocks/slab) -- best measured config.
// mode2=0: fp16 [p][c] OUTH. mode2=1: fp32 OUT with fp16 residuals.
__global__ __launch_bounds__(192) void k_convm(const _Float16* __restrict__ Xg,
    const _Float16* __restrict__ Wh, float* __restrict__ OUT, _Float16* __restrict__ OUTH,
    const _Float16* __restrict__ X1h, const _Float16* __restrict__ XresH,
    int mode2, int do_leaky){
  __shared__ _Float16 sB[338*32];                  // 21632 B
  int tid = threadIdx.x;
  int orig = blockIdx.x;                           // [0,1944)
  int xcd = orig & 7, loc = orig >> 3;
  int wg = xcd*243 + loc;
  int slab = wg/27, tb = wg - slab*27;
  int q0 = tb*192;
  int wid = tid >> 6;
  int lane = tid & 63;
  int l15 = lane & 15, kg = lane >> 4;
  f32x4 acc[2][4];
  f32x4 zz = {0.f,0.f,0.f,0.f};
  #pragma unroll
  for (int a=0;a<2;a++)
    #pragma unroll
    for (int b=0;b<4;b++) acc[a][b] = zz;
  int wbase = l15*32 + kg*8;
  int lbase = wid*64 + 73 + l15;                   // LDS row base for this lane
  for (int dx=0; dx<3; dx++){
    int xx = slab + dx - 1;
    if ((unsigned)xx >= 72u) continue;             // slab is block-uniform
    __syncthreads();                               // protect previous window reads
    {
      const f16x8* src = (const f16x8*)(Xg + ((long long)xx*5184 + q0 - 73)*32);
      f16x8* dst = (f16x8*)sB;
      for (int e=tid; e<1352; e+=192){
        int es = (e & ~3) | ((e & 3) ^ ((e >> 3) & 3));
        dst[es] = src[e];
      }
    }
    __syncthreads();
    const _Float16* Wdx = Wh + dx*9216;
    #pragma unroll
    for (int t9=0; t9<9; t9++){
      int off = ((t9/3)-1)*72 + (t9%3) - 1;
      const _Float16* wp = Wdx + t9*1024 + wbase;
      f16x8 a0 = *(const f16x8*)(wp);
      f16x8 a1 = *(const f16x8*)(wp + 512);
      int rr = lbase + off;
      const _Float16* bb = sB + (((rr << 2) | (kg ^ ((rr >> 1) & 3)))*8);
      f16x8 b0 = *(const f16x8*)(bb);
      f16x8 b1 = *(const f16x8*)(bb + 512);
      f16x8 b2 = *(const f16x8*)(bb + 1024);
      f16x8 b3 = *(const f16x8*)(bb + 1536);
      acc[0][0] = __builtin_amdgcn_mfma_f32_16x16x32_f16(a0,b0,acc[0][0],0,0,0);
      acc[0][1] = __builtin_amdgcn_mfma_f32_16x16x32_f16(a0,b1,acc[0][1],0,0,0);
      acc[0][2] = __builtin_amdgcn_mfma_f32_16x16x32_f16(a0,b2,acc[0][2],0,0,0);
      acc[0][3] = __builtin_amdgcn_mfma_f32_16x16x32_f16(a0,b3,acc[0][3],0,0,0);
      acc[1][0] = __builtin_amdgcn_mfma_f32_16x16x32_f16(a1,b0,acc[1][0],0,0,0);
      acc[1][1] = __builtin_amdgcn_mfma_f32_16x16x32_f16(a1,b1,acc[1][1],0,0,0);
      acc[1][2] = __builtin_amdgcn_mfma_f32_16x16x32_f16(a1,b2,acc[1][2],0,0,0);
      acc[1][3] = __builtin_amdgcn_mfma_f32_16x16x32_f16(a1,b3,acc[1][3],0,0,0);
    }
  }
  int q0w = q0 + wid*64;
  if (mode2){
    #pragma unroll
    for (int nt=0; nt<4; nt++){
      int q = q0w + nt*16 + l15;
      int y = q/72, z = q - y*72;
      bool edge = (y==0)||(y==71)||(z==0)||(z==71);
      #pragma unroll
      for (int c2=0;c2<2;c2++){
        #pragma unroll
        for (int r=0;r<4;r++){
          int co = c2*16 + kg*4 + r;
          size_t idx = (size_t)co*NS3 + (size_t)slab*5184 + q;
          float v = acc[c2][nt][r];
          if (!edge){
            v += (float)X1h[idx] + (float)XresH[((size_t)slab*5184 + q)*32 + co];
            if (do_leaky) v = leakyf(v);
          }
          OUT[idx] = v;
        }
      }
    }
  } else {
    #pragma unroll
    for (int nt=0; nt<4; nt++){
      int q = q0w + nt*16 + l15;
      int y = q/72, z = q - y*72;
      bool edge = (y==0)||(y==71)||(z==0)||(z==71);
      _Float16* hp = OUTH + ((size_t)slab*5184 + q)*32 + kg*4;
      #pragma unroll
      for (int c2=0;c2<2;c2++){
        f32x4 av = acc[c2][nt];
        f16x4 hv;
        #pragma unroll
        for (int r=0;r<4;r++){
          float v = av[r];
          if (!edge) v = leakyf(v);
          hv[r] = (_Float16)v;
        }
        *(f16x4*)(hp + c2*16) = hv;
      }
    }
  }
}

// fix boundary voxels of fp16 H in place (proven wrapped-tap semantics, x-skip)
__global__ void k_corrH(_Float16* __restrict__ H, const _Float16* __restrict__ Xg,
                        const _Float16* __restrict__ Wh){
  int t = blockIdx.x*256 + threadIdx.x;            // 654336
  int co = t & 31; int t2 = t >> 5;
  int e = t2 % 284; int x = t2 / 284;
  int y, z;
  if (e < 72){ y = 0; z = e; }
  else if (e < 144){ y = 71; z = e - 72; }
  else if (e < 214){ z = 0; y = e - 143; }
  else { z = 71; y = e - 213; }
  int q = y*72 + z;
  float corr = 0.f;
  for (int tap=0; tap<27; tap++){
    int dx = tap/9, rr = tap%9, dy = rr/3, dz = rr%3;
    int xx = x + dx - 1;
    if ((unsigned)xx >= 72u) continue;
    int yy = y + dy - 1, zz = z + dz - 1;
    if ((unsigned)yy < 72u && (unsigned)zz < 72u) continue;
    int lin = (xx*5184 + q + (dy-1)*72 + (dz-1))*32;
    const _Float16* V = Xg + lin;
    const _Float16* Wr = Wh + (tap*32 + co)*32;
    float s = 0.f;
    #pragma unroll
    for (int ci=0; ci<32; ci++) s += (float)V[ci]*(float)Wr[ci];
    corr += s;
  }
  size_t idx = ((size_t)x*5184 + q)*32 + co;
  float v = (float)H[idx] - corr;
  v = leakyf(v);
  H[idx] = (_Float16)v;
}

// fix boundary voxels (fp32 final output path, fp16 residuals)
__global__ void k_corr(float* __restrict__ OUT, const _Float16* __restrict__ Xg,
                       const _Float16* __restrict__ Wh, const _Float16* __restrict__ X1h,
                       const _Float16* __restrict__ XresH, int mode2, int do_leaky){
  int t = blockIdx.x*256 + threadIdx.x;            // 654336
  int co = t & 31; int t2 = t >> 5;
  int e = t2 % 284; int x = t2 / 284;
  int y, z;
  if (e < 72){ y = 0; z = e; }
  else if (e < 144){ y = 71; z = e - 72; }
  else if (e < 214){ z = 0; y = e - 143; }
  else { z = 71; y = e - 213; }
  int q = y*72 + z;
  float corr = 0.f;
  for (int tap=0; tap<27; tap++){
    int dx = tap/9, rr = tap%9, dy = rr/3, dz = rr%3;
    int xx = x + dx - 1;
    if ((unsigned)xx >= 72u) continue;
    int yy = y + dy - 1, zz = z + dz - 1;
    if ((unsigned)yy < 72u && (unsigned)zz < 72u) continue;
    int lin = (xx*5184 + q + (dy-1)*72 + (dz-1))*32;
    const _Float16* V = Xg + lin;
    const _Float16* Wr = Wh + (tap*32 + co)*32;
    float s = 0.f;
    #pragma unroll
    for (int ci=0; ci<32; ci++) s += (float)V[ci]*(float)Wr[ci];
    corr += s;
  }
  size_t idx = (size_t)co*NS3 + (size_t)x*5184 + q;
  float v = OUT[idx] - corr;
  if (mode2) v += (float)X1h[idx] + (float)XresH[((size_t)x*5184 + q)*32 + co];
  if (do_leaky) v = leakyf(v);
  OUT[idx] = v;
}

// crop to 64^3, fc1 (32->128) + leaky + fc2 (128->6); 2 voxels/thread.
// All weights via wave-uniform scalar loads (w1t transposed [j][c]) -- no LDS.
__global__ void k_head(const float* __restrict__ X, const float* __restrict__ w1t, const float* __restrict__ b1,
                       const float* __restrict__ w2, const float* __restrict__ b2, float* __restrict__ out){
  int tid = threadIdx.x;
  int p0 = blockIdx.x*256 + tid;                   // [0, 131072)
  float xin[2][32];
  float acc[2][6];
  float bb2[6];
  #pragma unroll
  for (int o=0;o<6;o++) bb2[o] = b2[o];
  #pragma unroll
  for (int vv=0; vv<2; vv++){
    int p = p0 + vv*131072;
    int z = p % 64; int t = p / 64; int y = t % 64; int x = t / 64;
    size_t q = ((size_t)x*NS + y)*NS + z;
    #pragma unroll
    for (int c=0;c<32;c++) xin[vv][c] = X[(size_t)c*NS3 + q];
    #pragma unroll
    for (int o=0;o<6;o++) acc[vv][o]=bb2[o];
  }
  for (int j=0;j<128;j++){
    const float4* wj = (const float4*)(w1t + j*32);
    float h0 = b1[j], h1 = h0;
    #pragma unroll
    for (int c4=0;c4<8;c4++){
      float4 w = wj[c4];
      h0 += xin[0][c4*4+0]*w.x + xin[0][c4*4+1]*w.y + xin[0][c4*4+2]*w.z + xin[0][c4*4+3]*w.w;
      h1 += xin[1][c4*4+0]*w.x + xin[1][c4*4+1]*w.y + xin[1][c4*4+2]*w.z + xin[1][c4*4+3]*w.w;
    }
    h0 = leakyf(h0); h1 = leakyf(h1);
    const float* s2j = w2 + j*6;
    #pragma unroll
    for (int o=0;o<6;o++){
      float wv = s2j[o];
      acc[0][o] += h0*wv;
      acc[1][o] += h1*wv;
    }
  }
  #pragma unroll
  for (int vv=0; vv<2; vv++){
    float* O = out + (size_t)(p0 + vv*131072)*6;
    #pragma unroll
    for (int o=0;o<6;o++) O[o]=acc[vv][o];
  }
}

extern "C" void kernel_launch(void* const* d_in, const int* in_sizes, int n_in,
                              void* d_out, int out_size, void* d_ws, size_t ws_size,
                              hipStream_t stream) {
  const float* yeex = (const float*)d_in[0];
  const float* yeey = (const float*)d_in[1];
  const float* yeez = (const float*)d_in[2];
  const float* fc0w = (const float*)d_in[3];
  const float* fc0b = (const float*)d_in[4];
  const float* specw= (const float*)d_in[5];
  const float* bw1  = (const float*)d_in[6];
  const float* bw2  = (const float*)d_in[7];
  const float* fc1w = (const float*)d_in[8];
  const float* fc1b = (const float*)d_in[9];
  const float* fc2w = (const float*)d_in[10];
  const float* fc2b = (const float*)d_in[11];
  float* out = (float*)d_out;
  float* ws  = (float*)d_ws;

  float*  P0 = ws;                                  // 11943936 floats
  float*  X1s = ws + 11943936;                      // X1h fp16 slot
  float*  P2 = ws + 23887872;
  float2* A  = (float2*)(ws + 35831808);            // spectral slots
  float2* B  = (float2*)(ws + 41140224);
  float2* Cf = (float2*)(ws + 46448640);
  float2* Df = (float2*)(ws + 51757056);
  float2* TW = (float2*)(ws + 57065472);
  float*  W1T = ws + 57065728;                      // 4096 floats (fc1 transposed)
  // freq-conv fp16 GEMM operands (overlay A/B slots; dead by conv phase)
  _Float16* Ah = (_Float16*)A;
  _Float16* Bg = (_Float16*)B;
  _Float16* X1h = (_Float16*)X1s;                   // fp16 spectral result
  // fp16 buffers for the spatial conv path (overlay spectral slots, used after invyz)
  _Float16* XhG = (_Float16*)(ws + 35831808) + 4096;  // guarded data ptr
  _Float16* HhG = (_Float16*)(ws + 41807872) + 4096;
  _Float16* WhA = (_Float16*)(ws + 47783936);         // 27648 fp16
  _Float16* WhB = (_Float16*)(ws + 47797760);

  float* curX = P0; float* curY = P2;

  k_tw<<<1,128,0,stream>>>(TW);
  k_wpackT<<<16,256,0,stream>>>(fc1w, W1T);
  // Df gap entries are never written by freqmfma2 and must read as zero:
  // one memset per launch suffices (freqmfma2 rewrites the same entry set
  // every layer).
  hipMemsetAsync(Df, 0, (size_t)1327104*8, stream);
  k_fc0<<<46656,256,0,stream>>>(yeex,yeey,yeez,fc0w,fc0b,curX);
  for (int i=0;i<4;i++){
    k_zdft<<<648,256,0,stream>>>(curX, A, TW);
    k_ydft<<<648,256,0,stream>>>(A, B, TW);
    k_xdftL<<<512,256,0,stream>>>(B, Cf, TW);
    k_pack<<<21184,256,0,stream>>>(specw + (size_t)i*8*64*64*125, Ah, Cf, Bg);
    k_freqmfma2<<<256,512,0,stream>>>(Ah, Bg, (float*)Df);
    k_invx<<<648,256,0,stream>>>(Df, A, TW);
    k_invyz<<<648,256,0,stream>>>(A, X1h, TW);
    // conv phase (spectral scratch now dead; overlay with fp16 buffers)
    k_cvtall<<<1678,256,0,stream>>>(curX, XhG, HhG,
                                    bw1 + (size_t)i*27648, bw2 + (size_t)i*27648, WhA, WhB);
    k_convm<<<1944,192,0,stream>>>(XhG, WhA, nullptr, HhG, nullptr, nullptr, 0, 1);
    k_corrH<<<2556,256,0,stream>>>(HhG, XhG, WhA);
    k_convm<<<1944,192,0,stream>>>(HhG, WhB, curY, nullptr, X1h, XhG, 1, (i<3)?1:0);
    k_corr<<<2556,256,0,stream>>>(curY, HhG, WhB, X1h, XhG, 1, (i<3)?1:0);
    float* tmp = curX; curX = curY; curY = tmp;
  }
  k_head<<<512,256,0,stream>>>(curX, W1T, fc1b, fc2w, fc2b, out);
}